// Round 19
// baseline (802.833 us; speedup 1.0000x reference)
//
#include <hip/hip_runtime.h>
#include <hip/hip_bf16.h>
#include <math.h>

typedef float f4 __attribute__((ext_vector_type(4)));

#define NEG 0.2f
#define BN_EPS 1e-5f

// compare-exchange on u64 keys, descending (larger first)
#define CE(K,A,B) { unsigned long long _x = K[A], _y = K[B]; bool _s = _x < _y; \
                    K[A] = _s ? _y : _x; K[B] = _s ? _x : _y; }

// ---- wave-64 reductions via DPP (VALU pipe, no ds_bpermute) -------------
__device__ __forceinline__ float wred_max_f32(float v) {
  int x = __float_as_int(v), y;
#define STEPM(C) y = __builtin_amdgcn_update_dpp(x, x, C, 0xf, 0xf, false); \
  x = __float_as_int(fmaxf(__int_as_float(x), __int_as_float(y)));
  STEPM(0x111) STEPM(0x112) STEPM(0x114) STEPM(0x118) STEPM(0x142) STEPM(0x143)
#undef STEPM
  return __int_as_float(__builtin_amdgcn_readlane(x, 63));
}
__device__ __forceinline__ float wred_sum_f32(float v) {
  int x = __float_as_int(v), y;
#define STEPS(C) y = __builtin_amdgcn_update_dpp(0, x, C, 0xf, 0xf, true); \
  x = __float_as_int(__int_as_float(x) + __int_as_float(y));
  STEPS(0x111) STEPS(0x112) STEPS(0x114) STEPS(0x118) STEPS(0x142) STEPS(0x143)
#undef STEPS
  return __int_as_float(__builtin_amdgcn_readlane(x, 63));
}
// u32 max: 4 DPP steps (per-16 prefix max) + 4 readlane + SALU max tree.
__device__ __forceinline__ unsigned wred16_max_u32(unsigned v) {
  int x = (int)v, y;
#define STEPU(C) y = __builtin_amdgcn_update_dpp(x, x, C, 0xf, 0xf, false); \
  x = (int)((unsigned)x > (unsigned)y ? (unsigned)x : (unsigned)y);
  STEPU(0x111) STEPU(0x112) STEPU(0x114) STEPU(0x118)
#undef STEPU
  unsigned a0 = (unsigned)__builtin_amdgcn_readlane(x, 15);
  unsigned a1 = (unsigned)__builtin_amdgcn_readlane(x, 31);
  unsigned a2 = (unsigned)__builtin_amdgcn_readlane(x, 47);
  unsigned a3 = (unsigned)__builtin_amdgcn_readlane(x, 63);
  unsigned m01 = a0 > a1 ? a0 : a1;
  unsigned m23 = a2 > a3 ? a2 : a3;
  return m01 > m23 ? m01 : m23;
}

__device__ __forceinline__ unsigned sel_round4(unsigned (&hi)[4], unsigned (&lo)[4],
                                               bool do_pop) {
  unsigned gv = wred16_max_u32(hi[0]);
  unsigned long long tied = __ballot(hi[0] == gv);
  unsigned gl;
  if (__popcll(tied) == 1) {
    int wl = __ffsll((long long)tied) - 1;
    gl = (unsigned)__builtin_amdgcn_readlane((int)lo[0], wl);
  } else {
    gl = wred16_max_u32((hi[0] == gv) ? lo[0] : 0u);
  }
  if (do_pop) {
    bool win = (hi[0] == gv) && (lo[0] == gl);
    hi[0] = win ? hi[1] : hi[0]; lo[0] = win ? lo[1] : lo[0];
    hi[1] = win ? hi[2] : hi[1]; lo[1] = win ? lo[2] : lo[1];
    hi[2] = win ? hi[3] : hi[2]; lo[2] = win ? lo[3] : lo[2];
    hi[3] = win ? 0u    : hi[3]; lo[3] = win ? 0u    : lo[3];
  }
  return gl;
}

// ---------------- Stage 1 attention (qkv fused): xt1, idx1 ----------------
__global__ __launch_bounds__(256) void attn1_k(const float* __restrict__ x,
    const float* __restrict__ Wq, const float* __restrict__ Wk,
    const float* __restrict__ Wv, float* __restrict__ xt1p, int* __restrict__ idx1,
    int g0) {
  __shared__ f4 kl[512];
  __shared__ f4 vl[512];
  __shared__ unsigned long long lists[4][2][6][64];  // [wave][pair][slot][lane]
  int t = threadIdx.x, g = blockIdx.y + g0;
  int w = t >> 6, l = t & 63;
  int nb = blockIdx.x * 16;
  const float* xr = x + (size_t)g * 1536;
  {
#pragma clang fp contract(off)
    for (int i = t; i < 512; i += 256) {
      float x0 = xr[i], x1v = xr[512 + i], x2v = xr[1024 + i];
      f4 kd, vd;
#pragma unroll
      for (int o = 0; o < 3; ++o) {
        kd[o] = x0 * Wk[o*3+0] + x1v * Wk[o*3+1] + x2v * Wk[o*3+2];
        vd[o] = x0 * Wv[o*3+0] + x1v * Wv[o*3+1] + x2v * Wv[o*3+2];
      }
      kd[3] = 0.f; vd[3] = 0.f;
      kl[i] = kd; vl[i] = vd;
    }
  }
  __syncthreads();
  for (int rp = 0; rp < 2; ++rp) {
    int nA = nb + rp * 8 + w;
    int nB = nA + 4;
    float xA0 = xr[nA], xA1 = xr[512 + nA], xA2 = xr[1024 + nA];
    float xB0 = xr[nB], xB1 = xr[512 + nB], xB2 = xr[1024 + nB];
    float qA0, qA1, qA2, qB0, qB1, qB2;
    float aA[8], aB[8];
    {
#pragma clang fp contract(off)
      qA0 = xA0*Wq[0] + xA1*Wq[1] + xA2*Wq[2];
      qA1 = xA0*Wq[3] + xA1*Wq[4] + xA2*Wq[5];
      qA2 = xA0*Wq[6] + xA1*Wq[7] + xA2*Wq[8];
      qB0 = xB0*Wq[0] + xB1*Wq[1] + xB2*Wq[2];
      qB1 = xB0*Wq[3] + xB1*Wq[4] + xB2*Wq[5];
      qB2 = xB0*Wq[6] + xB1*Wq[7] + xB2*Wq[8];
#pragma unroll
      for (int j = 0; j < 8; ++j) {
        f4 kk = kl[l + 64 * j];
        aA[j] = (qA0*kk[0] + qA1*kk[1] + qA2*kk[2]) / sqrtf(3.0f);
        aB[j] = (qB0*kk[0] + qB1*kk[1] + qB2*kk[2]) / sqrtf(3.0f);
      }
    }
    float mxA = aA[0], mxB = aB[0];
#pragma unroll
    for (int j = 1; j < 8; ++j) { mxA = fmaxf(mxA, aA[j]); mxB = fmaxf(mxB, aB[j]); }
    mxA = wred_max_f32(mxA); mxB = wred_max_f32(mxB);
    float wsA = 0.f, wsB = 0.f;
#pragma unroll
    for (int j = 0; j < 8; ++j) {
      aA[j] = expf(aA[j] - mxA); wsA += aA[j];
      aB[j] = expf(aB[j] - mxB); wsB += aB[j];
    }
    wsA = wred_sum_f32(wsA); wsB = wred_sum_f32(wsB);
#pragma unroll
    for (int j = 0; j < 8; ++j) { aA[j] = aA[j] / wsA; aB[j] = aB[j] / wsB; }
    float oA0 = 0.f, oA1 = 0.f, oA2 = 0.f, oB0 = 0.f, oB1 = 0.f, oB2 = 0.f;
#pragma unroll
    for (int j = 0; j < 8; ++j) {
      f4 vv = vl[l + 64 * j];
      oA0 += aA[j] * vv[0]; oA1 += aA[j] * vv[1]; oA2 += aA[j] * vv[2];
      oB0 += aB[j] * vv[0]; oB1 += aB[j] * vv[1]; oB2 += aB[j] * vv[2];
    }
    oA0 = wred_sum_f32(oA0); oA1 = wred_sum_f32(oA1); oA2 = wred_sum_f32(oA2);
    oB0 = wred_sum_f32(oB0); oB1 = wred_sum_f32(oB1); oB2 = wred_sum_f32(oB2);
    if (l == 0) {
      float* xo = xt1p + ((size_t)g * 512 + nA) * 4;
      xo[0] = xA0 + oA0; xo[1] = xA1 + oA1; xo[2] = xA2 + oA2;
      float* xo2 = xt1p + ((size_t)g * 512 + nB) * 4;
      xo2[0] = xB0 + oB0; xo2[1] = xB1 + oB1; xo2[2] = xB2 + oB2;
    }
    // ---- keys + per-lane sort ----
    unsigned long long keyA[8], keyB[8];
#pragma unroll
    for (int j = 0; j < 8; ++j) {
      unsigned idx = (unsigned)(l + 64 * j);
      keyA[j] = ((unsigned long long)__float_as_uint(aA[j]) << 32) | (unsigned)(~idx);
      keyB[j] = ((unsigned long long)__float_as_uint(aB[j]) << 32) | (unsigned)(~idx);
    }
    CE(keyA,0,1) CE(keyA,2,3) CE(keyA,4,5) CE(keyA,6,7)
    CE(keyA,0,2) CE(keyA,1,3) CE(keyA,4,6) CE(keyA,5,7)
    CE(keyA,1,2) CE(keyA,5,6)
    CE(keyA,0,4) CE(keyA,1,5) CE(keyA,2,6) CE(keyA,3,7)
    CE(keyA,2,4) CE(keyA,3,5)
    CE(keyA,1,2) CE(keyA,3,4) CE(keyA,5,6)
    CE(keyB,0,1) CE(keyB,2,3) CE(keyB,4,5) CE(keyB,6,7)
    CE(keyB,0,2) CE(keyB,1,3) CE(keyB,4,6) CE(keyB,5,7)
    CE(keyB,1,2) CE(keyB,5,6)
    CE(keyB,0,4) CE(keyB,1,5) CE(keyB,2,6) CE(keyB,3,7)
    CE(keyB,2,4) CE(keyB,3,5)
    CE(keyB,1,2) CE(keyB,3,4) CE(keyB,5,6)
    // spill slots 2..7 (slot-major: conflict-free); no sentinel slot
#pragma unroll
    for (int j = 2; j < 8; ++j) {
      lists[w][0][j - 2][l] = keyA[j];
      lists[w][1][j - 2][l] = keyB[j];
    }
    unsigned hHiA = (unsigned)(keyA[0] >> 32), hLoA = (unsigned)keyA[0];
    unsigned nHiA = (unsigned)(keyA[1] >> 32), nLoA = (unsigned)keyA[1];
    unsigned hHiB = (unsigned)(keyB[0] >> 32), hLoB = (unsigned)keyB[0];
    unsigned nHiB = (unsigned)(keyB[1] >> 32), nLoB = (unsigned)keyB[1];
    int slA = 0, slB = 0;
    unsigned long long pfA = lists[w][0][0][l], pfB = lists[w][1][0][l];
    int* ioA = idx1 + ((size_t)g * 512 + nA) * 20;
    int* ioB = idx1 + ((size_t)g * 512 + nB) * 20;
    for (int kk = 0; kk < 20; ++kk) {
      unsigned gvA = wred16_max_u32(hHiA);
      unsigned gvB = wred16_max_u32(hHiB);
      unsigned long long mA = __ballot(hHiA == gvA);
      unsigned long long mB = __ballot(hHiB == gvB);
      unsigned glA, glB;
      if (__popcll(mA) == 1) {
        int wl = __ffsll((long long)mA) - 1;
        glA = (unsigned)__builtin_amdgcn_readlane((int)hLoA, wl);
      } else glA = wred16_max_u32((hHiA == gvA) ? hLoA : 0u);
      if (__popcll(mB) == 1) {
        int wl = __ffsll((long long)mB) - 1;
        glB = (unsigned)__builtin_amdgcn_readlane((int)hLoB, wl);
      } else glB = wred16_max_u32((hHiB == gvB) ? hLoB : 0u);
      if (l == 0) { ioA[kk] = (int)(~glA); ioB[kk] = (int)(~glB); }
      if (kk < 19) {
        bool wA = (hHiA == gvA) && (hLoA == glA);
        hHiA = wA ? nHiA : hHiA; hLoA = wA ? nLoA : hLoA;
        nHiA = wA ? (unsigned)(pfA >> 32) : nHiA;
        nLoA = wA ? (unsigned)pfA : nLoA;
        slA = wA ? slA + 1 : slA;
        {
          int ixA = slA > 5 ? 5 : slA;
          unsigned long long rdA = lists[w][0][ixA][l];
          pfA = (slA > 5) ? 0ull : rdA;
        }
        bool wB = (hHiB == gvB) && (hLoB == glB);
        hHiB = wB ? nHiB : hHiB; hLoB = wB ? nLoB : hLoB;
        nHiB = wB ? (unsigned)(pfB >> 32) : nHiB;
        nLoB = wB ? (unsigned)pfB : nLoB;
        slB = wB ? slB + 1 : slB;
        {
          int ixB = slB > 5 ? 5 : slB;
          unsigned long long rdB = lists[w][1][ixB][l];
          pfB = (slB > 5) ? 0ull : rdB;
        }
      }
    }
  }
}

// ---------------- conv1 + bn1 + lrelu + max over k' ----------------------
__global__ __launch_bounds__(256) void conv1_k(const float* __restrict__ xt1p,
    const int* __restrict__ idx1, const float* __restrict__ w1,
    const float* __restrict__ bg, const float* __restrict__ bb,
    float* __restrict__ x1g) {
  __shared__ float wt[108][64];
  __shared__ float cwt[36][64];
  __shared__ __align__(16) float yfl[4][10][3][20];
  __shared__ float ycl[4][10][4];
  int t = threadIdx.x;
  int fp = blockIdx.y, b = blockIdx.z;
  int np0 = blockIdx.x * 16;
  int o = t & 63, part = t >> 6;
  for (int i = part; i < 108; i += 4) {
    int w3 = i % 3, rh = i / 3;
    int cc = rh / 12, dh = rh % 12;
    wt[i][o] = w1[o * 216 + cc * 36 + dh * 3 + w3];
  }
  for (int i = part; i < 36; i += 4) {
    int cc = i / 12, dh = i % 12;
    const float* ww = &w1[o * 216 + (cc + 3) * 36 + dh * 3];
    cwt[i][o] = ww[0] + ww[1] + ww[2];
  }
  int g2 = b * 8 + fp;
  for (int rnd = 0; rnd < 4; ++rnd) {
    int npr = np0 + rnd * 4;
    __syncthreads();
    for (int it = t; it < 800; it += 256) {
      int d = it / 200, rem = it % 200, nl = rem / 20, k = rem % 20;
      int n = 2 * npr + nl;
      if (n < 512) {
        int g = b * 32 + fp * 4 + d;
        int j = idx1[((size_t)g * 512 + n) * 20 + k];
        f4 vj = *(const f4*)(xt1p + ((size_t)g * 512 + j) * 4);
        f4 vc = *(const f4*)(xt1p + ((size_t)g * 512 + n) * 4);
        yfl[d][nl][0][k] = vj[0] - vc[0];
        yfl[d][nl][1][k] = vj[1] - vc[1];
        yfl[d][nl][2][k] = vj[2] - vc[2];
      } else {
        yfl[d][nl][0][k] = 0.f; yfl[d][nl][1][k] = 0.f; yfl[d][nl][2][k] = 0.f;
      }
    }
    if (t < 40) {
      int d = t / 10, nl = t % 10;
      int n = 2 * npr + nl;
      if (n < 512) {
        int g = b * 32 + fp * 4 + d;
        f4 vc = *(const f4*)(xt1p + ((size_t)g * 512 + n) * 4);
        ycl[d][nl][0] = vc[0]; ycl[d][nl][1] = vc[1]; ycl[d][nl][2] = vc[2];
      } else {
        ycl[d][nl][0] = 0.f; ycl[d][nl][1] = 0.f; ycl[d][nl][2] = 0.f;
      }
    }
    __syncthreads();
    int np = npr + part;
    if (np < 255) {
      float fa[18] = {0.f,0.f,0.f,0.f,0.f,0.f,0.f,0.f,0.f,
                      0.f,0.f,0.f,0.f,0.f,0.f,0.f,0.f,0.f};
      float ctr = 0.f;
      for (int cc = 0; cc < 3; ++cc) {
        for (int dh = 0; dh < 12; ++dh) {
          int d = dh / 3, h = dh % 3;
          int nl = 2 * part + h;
          int ib = (cc * 12 + dh) * 3;
          float w0 = wt[ib][o], w1v = wt[ib + 1][o], w2v = wt[ib + 2][o];
          ctr += ycl[d][nl][cc] * cwt[cc * 12 + dh][o];
          const f4* yr = (const f4*)&yfl[d][nl][cc][0];
          float y[20];
#pragma unroll
          for (int q = 0; q < 5; ++q) {
            f4 v = yr[q];
            y[4*q+0] = v[0]; y[4*q+1] = v[1]; y[4*q+2] = v[2]; y[4*q+3] = v[3];
          }
#pragma unroll
          for (int kp = 0; kp < 18; ++kp)
            fa[kp] += w0 * y[kp] + w1v * y[kp + 1] + w2v * y[kp + 2];
        }
      }
      float vmax = fa[0];
#pragma unroll
      for (int kp = 1; kp < 18; ++kp) vmax = fmaxf(vmax, fa[kp]);
      vmax += ctr;
      float sc = bg[o] / sqrtf(1.0f + BN_EPS);
      float z = sc * vmax + bb[o];
      if (z < 0.f) z *= NEG;
      x1g[((size_t)g2 * 255 + np) * 64 + o] = z;
    }
  }
}

// ---------------- Stage 2: q2,k2,v2 (32 rows/block) ----------------------
__global__ __launch_bounds__(256) void qkv2_k(const float* __restrict__ x1g,
    const float* __restrict__ Wq, const float* __restrict__ Wk, const float* __restrict__ Wv,
    float* __restrict__ q2, float* __restrict__ k2, float* __restrict__ v2) {
  __shared__ float Wl[3][64 * 65];
  __shared__ float rowl[4][64];
  int t = threadIdx.x, g = blockIdx.y;
  int w = t >> 6, l = t & 63;
  for (int i = t; i < 4096; i += 256) {
    int r = i >> 6, c = i & 63;
    Wl[0][r * 65 + c] = Wq[i];
    Wl[1][r * 65 + c] = Wk[i];
    Wl[2][r * 65 + c] = Wv[i];
  }
  __syncthreads();
  for (int rr = 0; rr < 8; ++rr) {
    int n = blockIdx.x * 32 + rr * 4 + w;
    bool valid = n < 255;
    rowl[w][l] = valid ? x1g[((size_t)g * 255 + n) * 64 + l] : 0.f;
    float qa = 0.f, ka = 0.f, va = 0.f;
    for (int c = 0; c < 64; ++c) {
      float rv = rowl[w][c];
      qa += rv * Wl[0][l * 65 + c];
      ka += rv * Wl[1][l * 65 + c];
      va += rv * Wl[2][l * 65 + c];
    }
    if (valid) {
      size_t off = ((size_t)g * 255 + n) * 64 + l;
      q2[off] = qa; k2[off] = ka; v2[off] = va;
    }
  }
}

// ---------------- Stage 2 attention: xt2, idx2 (64 rows/block) -----------
__global__ __launch_bounds__(512, 2) void attn2_k(const float* __restrict__ q2,
    const float* __restrict__ k2, const float* __restrict__ v2,
    const float* __restrict__ x1g, float* __restrict__ xt2, int* __restrict__ idx2) {
  __shared__ __align__(16) float Kl[255 * 64];   // word: m*64 + (c4^((m&7)<<2))
  __shared__ __align__(16) float Vl[255 * 64];   // linear [m][c]
  __shared__ __align__(16) float pl[8][2][256];  // [wave][row][m] (m=255 -> 0)
  __shared__ __align__(16) float ql[8][2][64];
  int t = threadIdx.x, g = blockIdx.x;
  int w = t >> 6, l = t & 63;
  int n0 = blockIdx.y * 64;
  const float* kg = k2 + (size_t)g * 16320;
  const float* vg = v2 + (size_t)g * 16320;
#pragma unroll 2
  for (int i = t; i < 4080; i += 512) {
    int m = i >> 4, c4 = (i & 15) << 2;
    f4 kv = *(const f4*)(kg + (size_t)i * 4);
    f4 vv = *(const f4*)(vg + (size_t)i * 4);
    *(f4*)&Kl[m * 64 + (c4 ^ ((m & 7) << 2))] = kv;
    *(f4*)&Vl[m * 64 + c4] = vv;
  }
  __syncthreads();
  for (int grp = 0; grp < 4; ++grp) {
    int rbase = n0 + w * 8 + grp * 2;
#pragma unroll
    for (int r = 0; r < 2; ++r) {
      int n = rbase + r;
      ql[w][r][l] = (n < 255) ? q2[((size_t)g * 255 + n) * 64 + l] : 0.f;
    }
    float s[2][4] = {};
#pragma unroll 2
    for (int c4 = 0; c4 < 64; c4 += 4) {
      f4 kv[4];
#pragma unroll
      for (int j = 0; j < 4; ++j) {
        int m = l + 64 * j;
        kv[j] = *(const f4*)&Kl[m * 64 + (c4 ^ ((m & 7) << 2))];
      }
#pragma unroll
      for (int r = 0; r < 2; ++r) {
        f4 qv = *(const f4*)&ql[w][r][c4];
#pragma unroll
        for (int j = 0; j < 4; ++j)
          s[r][j] += qv[0]*kv[j][0] + qv[1]*kv[j][1] + qv[2]*kv[j][2] + qv[3]*kv[j][3];
      }
    }
    unsigned Hi[2][4], Lo[2][4];
#pragma unroll
    for (int r = 0; r < 2; ++r) {
#pragma unroll
      for (int j = 0; j < 4; ++j) s[r][j] = s[r][j] / 8.0f;
      if (l == 63) s[r][3] = -1e30f;              // m = 255 invalid
      float mx = fmaxf(fmaxf(s[r][0], s[r][1]), fmaxf(s[r][2], s[r][3]));
      mx = wred_max_f32(mx);
      float ws = 0.f;
#pragma unroll
      for (int j = 0; j < 4; ++j) { s[r][j] = expf(s[r][j] - mx); ws += s[r][j]; }
      ws = wred_sum_f32(ws);
      unsigned long long key[4];
#pragma unroll
      for (int j = 0; j < 4; ++j) {
        s[r][j] = s[r][j] / ws;
        pl[w][r][64 * j + l] = s[r][j];
        key[j] = ((unsigned long long)__float_as_uint(s[r][j]) << 32)
               | (unsigned)(~(unsigned)(64 * j + l));
      }
      CE(key,0,1) CE(key,2,3) CE(key,0,2) CE(key,1,3) CE(key,1,2)
#pragma unroll
      for (int j = 0; j < 4; ++j) {
        Hi[r][j] = (unsigned)(key[j] >> 32); Lo[r][j] = (unsigned)key[j];
      }
    }
    float acc[2] = {0.f, 0.f};
#pragma unroll 4
    for (int m4 = 0; m4 < 256; m4 += 4) {
      f4 pv[2];
#pragma unroll
      for (int r = 0; r < 2; ++r) pv[r] = *(const f4*)&pl[w][r][m4];
      float v0 = Vl[(m4 + 0) * 64 + l];
      float v1 = Vl[(m4 + 1) * 64 + l];
      float v2v = Vl[(m4 + 2) * 64 + l];
      float v3 = Vl[(m4 + 3) * 64 + l];
#pragma unroll
      for (int r = 0; r < 2; ++r)
        acc[r] += pv[r][0]*v0 + pv[r][1]*v1 + pv[r][2]*v2v + pv[r][3]*v3;
    }
#pragma unroll
    for (int r = 0; r < 2; ++r) {
      int n = rbase + r;
      if (n < 255) {
        size_t off = ((size_t)g * 255 + n) * 64 + l;
        xt2[off] = x1g[off] + acc[r];
      }
    }
    int* io0 = idx2 + ((size_t)g * 255 + rbase + 0) * 20;
    int* io1 = idx2 + ((size_t)g * 255 + rbase + 1) * 20;
    for (int kk = 0; kk < 20; ++kk) {
      unsigned g0 = sel_round4(Hi[0], Lo[0], kk < 19);
      unsigned g1 = sel_round4(Hi[1], Lo[1], kk < 19);
      if (l == 0) {
        if (rbase + 0 < 255) io0[kk] = (int)(~g0);
        if (rbase + 1 < 255) io1[kk] = (int)(~g1);
      }
    }
  }
}

// ---------------- w2 transpose: w2T[c][o] --------------------------------
__global__ __launch_bounds__(256) void w2t_k(const float* __restrict__ w2,
                                             float* __restrict__ w2T) {
  int t = threadIdx.x;
  for (int i = t; i < 16384; i += 256) {
    int o = i >> 7, c = i & 127;
    w2T[c * 128 + o] = w2[o * 128 + c];
  }
}

// ---------------- conv2 (1x1, 128x128) + bn2 + lrelu + max over k --------
// Weights read from global w2T[c][o] (L1/L2-hot, shared by all blocks);
// LDS = rowsT 40KB + ctr 2KB = 42KB -> 3 blocks/CU (was 75.8KB -> 2).
// Same two sequential c-half loops as before -> bit-identical sums.
__global__ __launch_bounds__(256) void conv2_k(const float* __restrict__ xt2,
    const int* __restrict__ idx2, const float* __restrict__ w2T,
    const float* __restrict__ bg, const float* __restrict__ bb,
    float* __restrict__ x2g) {
  __shared__ __align__(16) float rowsT[8][64][20];  // [pos][c][k]
  __shared__ float ctr2[8][64];                     // [pos][c]
  int t = threadIdx.x, g = blockIdx.y;
  int n0 = blockIdx.x * 8;
  for (int i = t; i < 10240; i += 256) {
    int pos = i / 1280, rem = i % 1280, k = rem >> 6, c = rem & 63;
    int n = n0 + pos;
    float v = 0.f;
    if (n < 255) {
      int j = idx2[((size_t)g * 255 + n) * 20 + k];
      v = xt2[((size_t)g * 255 + j) * 64 + c];
    }
    rowsT[pos][c][k] = v;
  }
  for (int i = t; i < 512; i += 256) {
    int pos = i >> 6, c = i & 63;
    int n = n0 + pos;
    ctr2[pos][c] = (n < 255) ? xt2[((size_t)g * 255 + n) * 64 + c] : 0.f;
  }
  __syncthreads();
  int os = t & 31, np = t >> 5;
  float acc[4][20] = {};
  float t1[4] = {0.f, 0.f, 0.f, 0.f};
  for (int c = 0; c < 64; ++c) {
    f4 wq = *(const f4*)(w2T + c * 128 + os * 4);
    float cv = ctr2[np][c];
#pragma unroll
    for (int i = 0; i < 4; ++i) t1[i] += wq[i] * cv;
#pragma unroll
    for (int q = 0; q < 5; ++q) {
      f4 rv = *(const f4*)&rowsT[np][c][4 * q];
#pragma unroll
      for (int e = 0; e < 4; ++e)
#pragma unroll
        for (int i = 0; i < 4; ++i) acc[i][4 * q + e] += wq[i] * rv[e];
    }
  }
  float t2[4] = {0.f, 0.f, 0.f, 0.f};
  for (int c = 0; c < 64; ++c) {
    f4 wq = *(const f4*)(w2T + (64 + c) * 128 + os * 4);
    float cv = ctr2[np][c];
#pragma unroll
    for (int i = 0; i < 4; ++i) t2[i] += wq[i] * cv;
  }
  int n = n0 + np;
  f4 res;
#pragma unroll
  for (int i = 0; i < 4; ++i) {
    float vm = -1e30f;
#pragma unroll
    for (int j = 0; j < 20; ++j) vm = fmaxf(vm, acc[i][j]);
    vm += t2[i] - t1[i];
    int o = os * 4 + i;
    float sc = bg[o] / sqrtf(1.0f + BN_EPS);
    float z = sc * vm + bb[o];
    if (z < 0.f) z *= NEG;
    res[i] = z;
  }
  if (n < 255)
    *(f4*)&x2g[((size_t)g * 255 + n) * 128 + os * 4] = res;
}

// ---------------- conv5 (1x1, 1024x192) + bn5 + lrelu + max over n -------
__global__ __launch_bounds__(256) void conv5_k(const float* __restrict__ x1g,
    const float* __restrict__ x2g, const float* __restrict__ w5,
    const float* __restrict__ bg, const float* __restrict__ bb,
    float* __restrict__ out, int ot0) {
  __shared__ __align__(16) float w5h[96 * 64];
  __shared__ __align__(16) float colhT[96][68];   // [c][n(64)+pad]
  __shared__ float red[16][64];
  int t = threadIdx.x;
  int px = blockIdx.x, ot = blockIdx.y + ot0;
  int fp = px & 7, b = px >> 3;
  size_t rowbase = ((size_t)b * 8 + fp) * 255;
  int os = t & 15, ns = t >> 4;
  float acc[4][4][4] = {};   // [grp][o4][n4]
  for (int ch = 0; ch < 2; ++ch) {
    __syncthreads();
    for (int i = t; i < 6144; i += 256) {
      int oL = i / 96, c = i % 96;
      w5h[c * 64 + (oL ^ (c & 28))] = w5[((size_t)(ot * 64 + oL)) * 192 + ch * 96 + c];
    }
#pragma unroll
    for (int grp = 0; grp < 4; ++grp) {
      __syncthreads();
      for (int i = t; i < 6144; i += 256) {
        int nl = i / 96, c = i % 96;
        int n = grp * 64 + nl;
        float v = 0.f;
        if (n < 255) {
          int cc = ch * 96 + c;
          v = (cc < 64) ? x1g[(rowbase + n) * 64 + cc]
                        : x2g[(rowbase + n) * 128 + (cc - 64)];
        }
        colhT[c][nl] = v;
      }
      __syncthreads();
      for (int c = 0; c < 96; ++c) {
        f4 wq = *(const f4*)&w5h[c * 64 + ((os * 4) ^ (c & 28))];
        f4 cv = *(const f4*)&colhT[c][ns * 4];
#pragma unroll
        for (int u = 0; u < 4; ++u)
#pragma unroll
          for (int vv = 0; vv < 4; ++vv) acc[grp][u][vv] += wq[u] * cv[vv];
      }
    }
  }
  float vm[4] = {-1e30f, -1e30f, -1e30f, -1e30f};
#pragma unroll
  for (int grp = 0; grp < 4; ++grp)
#pragma unroll
    for (int vv = 0; vv < 4; ++vv) {
      int n = grp * 64 + ns * 4 + vv;
      if (n < 255)
#pragma unroll
        for (int u = 0; u < 4; ++u) vm[u] = fmaxf(vm[u], acc[grp][u][vv]);
    }
#pragma unroll
  for (int u = 0; u < 4; ++u) red[ns][os * 4 + u] = vm[u];
  __syncthreads();
  if (t < 64) {
    float m = -1e30f;
#pragma unroll
    for (int q = 0; q < 16; ++q) m = fmaxf(m, red[q][t]);
    int o = ot * 64 + t;
    float sc = bg[o] / sqrtf(1.0f + BN_EPS);
    float z = sc * m + bb[o];
    if (z < 0.f) z *= NEG;
    out[((size_t)b * 8 + fp) * 1024 + o] = z;
  }
}

// ---------------- launcher ----------------------------------------------
extern "C" void kernel_launch(void* const* d_in, const int* in_sizes, int n_in,
                              void* d_out, int out_size, void* d_ws, size_t ws_size,
                              hipStream_t stream) {
  const float* x   = (const float*)d_in[0];
  const float* Wq1 = (const float*)d_in[1];
  const float* Wk1 = (const float*)d_in[2];
  const float* Wv1 = (const float*)d_in[3];
  const float* Wq2 = (const float*)d_in[4];
  const float* Wk2 = (const float*)d_in[5];
  const float* Wv2 = (const float*)d_in[6];
  const float* w1  = (const float*)d_in[7];
  const float* w2  = (const float*)d_in[8];
  const float* w5  = (const float*)d_in[9];
  const float* bg1 = (const float*)d_in[10];
  const float* bb1 = (const float*)d_in[11];
  const float* bg2 = (const float*)d_in[12];
  const float* bb2 = (const float*)d_in[13];
  const float* bg5 = (const float*)d_in[14];
  const float* bb5 = (const float*)d_in[15];
  float* out = (float*)d_out;
  float* ws  = (float*)d_ws;

  float* x1g  = ws;                       // 1044480
  float* xt1p = ws + 1048576;             // 524288
  int*   idx1 = (int*)(ws + 1572864);     // 2621440
  float* q2   = ws + 4194304;             // 1044480
  float* k2   = ws + 5238784;             // 1044480
  float* v2   = ws + 6283264;             // 1044480
  float* xt2  = ws + 7327744;             // 1044480
  int*   idx2 = (int*)(ws + 8372224);     // 326400
  float* x2g  = ws + 8698624;             // 2088960
  float* w2T  = ws + 10787584;            // 16384

  attn1_k<<<dim3(32, 64), 256, 0, stream>>>(x, Wq1, Wk1, Wv1, xt1p, idx1, 0);
  attn1_k<<<dim3(32, 64), 256, 0, stream>>>(x, Wq1, Wk1, Wv1, xt1p, idx1, 64);
  attn1_k<<<dim3(32, 64), 256, 0, stream>>>(x, Wq1, Wk1, Wv1, xt1p, idx1, 128);
  attn1_k<<<dim3(32, 64), 256, 0, stream>>>(x, Wq1, Wk1, Wv1, xt1p, idx1, 192);
  conv1_k<<<dim3(16, 8, 8), 256, 0, stream>>>(xt1p, idx1, w1, bg1, bb1, x1g);
  qkv2_k<<<dim3(8, 64), 256, 0, stream>>>(x1g, Wq2, Wk2, Wv2, q2, k2, v2);
  attn2_k<<<dim3(64, 4), 512, 0, stream>>>(q2, k2, v2, x1g, xt2, idx2);
  w2t_k<<<dim3(1), 256, 0, stream>>>(w2, w2T);
  conv2_k<<<dim3(32, 64), 256, 0, stream>>>(xt2, idx2, w2T, bg2, bb2, x2g);
  conv5_k<<<dim3(64, 8), 256, 0, stream>>>(x1g, x2g, w5, bg5, bb5, out, 0);
  conv5_k<<<dim3(64, 8), 256, 0, stream>>>(x1g, x2g, w5, bg5, bb5, out, 8);
}

// Round 20
// 779.974 us; speedup vs baseline: 1.0293x; 1.0293x over previous
//
#include <hip/hip_runtime.h>
#include <hip/hip_bf16.h>
#include <math.h>

typedef float f4 __attribute__((ext_vector_type(4)));

#define NEG 0.2f
#define BN_EPS 1e-5f

// compare-exchange on u64 keys, descending (larger first)
#define CE(K,A,B) { unsigned long long _x = K[A], _y = K[B]; bool _s = _x < _y; \
                    K[A] = _s ? _y : _x; K[B] = _s ? _x : _y; }

// ---- wave-64 reductions via DPP (VALU pipe, no ds_bpermute) -------------
__device__ __forceinline__ float wred_max_f32(float v) {
  int x = __float_as_int(v), y;
#define STEPM(C) y = __builtin_amdgcn_update_dpp(x, x, C, 0xf, 0xf, false); \
  x = __float_as_int(fmaxf(__int_as_float(x), __int_as_float(y)));
  STEPM(0x111) STEPM(0x112) STEPM(0x114) STEPM(0x118) STEPM(0x142) STEPM(0x143)
#undef STEPM
  return __int_as_float(__builtin_amdgcn_readlane(x, 63));
}
__device__ __forceinline__ float wred_sum_f32(float v) {
  int x = __float_as_int(v), y;
#define STEPS(C) y = __builtin_amdgcn_update_dpp(0, x, C, 0xf, 0xf, true); \
  x = __float_as_int(__int_as_float(x) + __int_as_float(y));
  STEPS(0x111) STEPS(0x112) STEPS(0x114) STEPS(0x118) STEPS(0x142) STEPS(0x143)
#undef STEPS
  return __int_as_float(__builtin_amdgcn_readlane(x, 63));
}
// u32 max: 4 DPP steps (per-16 prefix max) + 4 readlane + SALU max tree.
__device__ __forceinline__ unsigned wred16_max_u32(unsigned v) {
  int x = (int)v, y;
#define STEPU(C) y = __builtin_amdgcn_update_dpp(x, x, C, 0xf, 0xf, false); \
  x = (int)((unsigned)x > (unsigned)y ? (unsigned)x : (unsigned)y);
  STEPU(0x111) STEPU(0x112) STEPU(0x114) STEPU(0x118)
#undef STEPU
  unsigned a0 = (unsigned)__builtin_amdgcn_readlane(x, 15);
  unsigned a1 = (unsigned)__builtin_amdgcn_readlane(x, 31);
  unsigned a2 = (unsigned)__builtin_amdgcn_readlane(x, 47);
  unsigned a3 = (unsigned)__builtin_amdgcn_readlane(x, 63);
  unsigned m01 = a0 > a1 ? a0 : a1;
  unsigned m23 = a2 > a3 ? a2 : a3;
  return m01 > m23 ? m01 : m23;
}

__device__ __forceinline__ unsigned sel_round4(unsigned (&hi)[4], unsigned (&lo)[4],
                                               bool do_pop) {
  unsigned gv = wred16_max_u32(hi[0]);
  unsigned long long tied = __ballot(hi[0] == gv);
  unsigned gl;
  if (__popcll(tied) == 1) {
    int wl = __ffsll((long long)tied) - 1;
    gl = (unsigned)__builtin_amdgcn_readlane((int)lo[0], wl);
  } else {
    gl = wred16_max_u32((hi[0] == gv) ? lo[0] : 0u);
  }
  if (do_pop) {
    bool win = (hi[0] == gv) && (lo[0] == gl);
    hi[0] = win ? hi[1] : hi[0]; lo[0] = win ? lo[1] : lo[0];
    hi[1] = win ? hi[2] : hi[1]; lo[1] = win ? lo[2] : lo[1];
    hi[2] = win ? hi[3] : hi[2]; lo[2] = win ? lo[3] : lo[2];
    hi[3] = win ? 0u    : hi[3]; lo[3] = win ? 0u    : lo[3];
  }
  return gl;
}

// ---------------- Stage 1 attention (qkv fused): xt1, idx1 ----------------
__global__ __launch_bounds__(256) void attn1_k(const float* __restrict__ x,
    const float* __restrict__ Wq, const float* __restrict__ Wk,
    const float* __restrict__ Wv, float* __restrict__ xt1p, int* __restrict__ idx1,
    int g0) {
  __shared__ f4 kl[512];
  __shared__ f4 vl[512];
  __shared__ unsigned long long lists[4][2][6][64];  // [wave][pair][slot][lane]
  int t = threadIdx.x, g = blockIdx.y + g0;
  int w = t >> 6, l = t & 63;
  int nb = blockIdx.x * 16;
  const float* xr = x + (size_t)g * 1536;
  {
#pragma clang fp contract(off)
    for (int i = t; i < 512; i += 256) {
      float x0 = xr[i], x1v = xr[512 + i], x2v = xr[1024 + i];
      f4 kd, vd;
#pragma unroll
      for (int o = 0; o < 3; ++o) {
        kd[o] = x0 * Wk[o*3+0] + x1v * Wk[o*3+1] + x2v * Wk[o*3+2];
        vd[o] = x0 * Wv[o*3+0] + x1v * Wv[o*3+1] + x2v * Wv[o*3+2];
      }
      kd[3] = 0.f; vd[3] = 0.f;
      kl[i] = kd; vl[i] = vd;
    }
  }
  __syncthreads();
  for (int rp = 0; rp < 2; ++rp) {
    int nA = nb + rp * 8 + w;
    int nB = nA + 4;
    float xA0 = xr[nA], xA1 = xr[512 + nA], xA2 = xr[1024 + nA];
    float xB0 = xr[nB], xB1 = xr[512 + nB], xB2 = xr[1024 + nB];
    float qA0, qA1, qA2, qB0, qB1, qB2;
    float aA[8], aB[8];
    {
#pragma clang fp contract(off)
      qA0 = xA0*Wq[0] + xA1*Wq[1] + xA2*Wq[2];
      qA1 = xA0*Wq[3] + xA1*Wq[4] + xA2*Wq[5];
      qA2 = xA0*Wq[6] + xA1*Wq[7] + xA2*Wq[8];
      qB0 = xB0*Wq[0] + xB1*Wq[1] + xB2*Wq[2];
      qB1 = xB0*Wq[3] + xB1*Wq[4] + xB2*Wq[5];
      qB2 = xB0*Wq[6] + xB1*Wq[7] + xB2*Wq[8];
#pragma unroll
      for (int j = 0; j < 8; ++j) {
        f4 kk = kl[l + 64 * j];
        aA[j] = (qA0*kk[0] + qA1*kk[1] + qA2*kk[2]) / sqrtf(3.0f);
        aB[j] = (qB0*kk[0] + qB1*kk[1] + qB2*kk[2]) / sqrtf(3.0f);
      }
    }
    float mxA = aA[0], mxB = aB[0];
#pragma unroll
    for (int j = 1; j < 8; ++j) { mxA = fmaxf(mxA, aA[j]); mxB = fmaxf(mxB, aB[j]); }
    mxA = wred_max_f32(mxA); mxB = wred_max_f32(mxB);
    float wsA = 0.f, wsB = 0.f;
#pragma unroll
    for (int j = 0; j < 8; ++j) {
      aA[j] = expf(aA[j] - mxA); wsA += aA[j];
      aB[j] = expf(aB[j] - mxB); wsB += aB[j];
    }
    wsA = wred_sum_f32(wsA); wsB = wred_sum_f32(wsB);
#pragma unroll
    for (int j = 0; j < 8; ++j) { aA[j] = aA[j] / wsA; aB[j] = aB[j] / wsB; }
    float oA0 = 0.f, oA1 = 0.f, oA2 = 0.f, oB0 = 0.f, oB1 = 0.f, oB2 = 0.f;
#pragma unroll
    for (int j = 0; j < 8; ++j) {
      f4 vv = vl[l + 64 * j];
      oA0 += aA[j] * vv[0]; oA1 += aA[j] * vv[1]; oA2 += aA[j] * vv[2];
      oB0 += aB[j] * vv[0]; oB1 += aB[j] * vv[1]; oB2 += aB[j] * vv[2];
    }
    oA0 = wred_sum_f32(oA0); oA1 = wred_sum_f32(oA1); oA2 = wred_sum_f32(oA2);
    oB0 = wred_sum_f32(oB0); oB1 = wred_sum_f32(oB1); oB2 = wred_sum_f32(oB2);
    if (l == 0) {
      float* xo = xt1p + ((size_t)g * 512 + nA) * 4;
      xo[0] = xA0 + oA0; xo[1] = xA1 + oA1; xo[2] = xA2 + oA2;
      float* xo2 = xt1p + ((size_t)g * 512 + nB) * 4;
      xo2[0] = xB0 + oB0; xo2[1] = xB1 + oB1; xo2[2] = xB2 + oB2;
    }
    // ---- keys + per-lane sort ----
    unsigned long long keyA[8], keyB[8];
#pragma unroll
    for (int j = 0; j < 8; ++j) {
      unsigned idx = (unsigned)(l + 64 * j);
      keyA[j] = ((unsigned long long)__float_as_uint(aA[j]) << 32) | (unsigned)(~idx);
      keyB[j] = ((unsigned long long)__float_as_uint(aB[j]) << 32) | (unsigned)(~idx);
    }
    CE(keyA,0,1) CE(keyA,2,3) CE(keyA,4,5) CE(keyA,6,7)
    CE(keyA,0,2) CE(keyA,1,3) CE(keyA,4,6) CE(keyA,5,7)
    CE(keyA,1,2) CE(keyA,5,6)
    CE(keyA,0,4) CE(keyA,1,5) CE(keyA,2,6) CE(keyA,3,7)
    CE(keyA,2,4) CE(keyA,3,5)
    CE(keyA,1,2) CE(keyA,3,4) CE(keyA,5,6)
    CE(keyB,0,1) CE(keyB,2,3) CE(keyB,4,5) CE(keyB,6,7)
    CE(keyB,0,2) CE(keyB,1,3) CE(keyB,4,6) CE(keyB,5,7)
    CE(keyB,1,2) CE(keyB,5,6)
    CE(keyB,0,4) CE(keyB,1,5) CE(keyB,2,6) CE(keyB,3,7)
    CE(keyB,2,4) CE(keyB,3,5)
    CE(keyB,1,2) CE(keyB,3,4) CE(keyB,5,6)
    // spill slots 2..7 (slot-major: conflict-free); no sentinel slot
#pragma unroll
    for (int j = 2; j < 8; ++j) {
      lists[w][0][j - 2][l] = keyA[j];
      lists[w][1][j - 2][l] = keyB[j];
    }
    unsigned hHiA = (unsigned)(keyA[0] >> 32), hLoA = (unsigned)keyA[0];
    unsigned nHiA = (unsigned)(keyA[1] >> 32), nLoA = (unsigned)keyA[1];
    unsigned hHiB = (unsigned)(keyB[0] >> 32), hLoB = (unsigned)keyB[0];
    unsigned nHiB = (unsigned)(keyB[1] >> 32), nLoB = (unsigned)keyB[1];
    int slA = 0, slB = 0;
    unsigned long long pfA = lists[w][0][0][l], pfB = lists[w][1][0][l];
    int* ioA = idx1 + ((size_t)g * 512 + nA) * 20;
    int* ioB = idx1 + ((size_t)g * 512 + nB) * 20;
    for (int kk = 0; kk < 20; ++kk) {
      unsigned gvA = wred16_max_u32(hHiA);
      unsigned gvB = wred16_max_u32(hHiB);
      unsigned long long mA = __ballot(hHiA == gvA);
      unsigned long long mB = __ballot(hHiB == gvB);
      unsigned glA, glB;
      if (__popcll(mA) == 1) {
        int wl = __ffsll((long long)mA) - 1;
        glA = (unsigned)__builtin_amdgcn_readlane((int)hLoA, wl);
      } else glA = wred16_max_u32((hHiA == gvA) ? hLoA : 0u);
      if (__popcll(mB) == 1) {
        int wl = __ffsll((long long)mB) - 1;
        glB = (unsigned)__builtin_amdgcn_readlane((int)hLoB, wl);
      } else glB = wred16_max_u32((hHiB == gvB) ? hLoB : 0u);
      if (l == 0) { ioA[kk] = (int)(~glA); ioB[kk] = (int)(~glB); }
      if (kk < 19) {
        bool wA = (hHiA == gvA) && (hLoA == glA);
        hHiA = wA ? nHiA : hHiA; hLoA = wA ? nLoA : hLoA;
        nHiA = wA ? (unsigned)(pfA >> 32) : nHiA;
        nLoA = wA ? (unsigned)pfA : nLoA;
        slA = wA ? slA + 1 : slA;
        {
          int ixA = slA > 5 ? 5 : slA;
          unsigned long long rdA = lists[w][0][ixA][l];
          pfA = (slA > 5) ? 0ull : rdA;
        }
        bool wB = (hHiB == gvB) && (hLoB == glB);
        hHiB = wB ? nHiB : hHiB; hLoB = wB ? nLoB : hLoB;
        nHiB = wB ? (unsigned)(pfB >> 32) : nHiB;
        nLoB = wB ? (unsigned)pfB : nLoB;
        slB = wB ? slB + 1 : slB;
        {
          int ixB = slB > 5 ? 5 : slB;
          unsigned long long rdB = lists[w][1][ixB][l];
          pfB = (slB > 5) ? 0ull : rdB;
        }
      }
    }
  }
}

// ---------------- conv1 + bn1 + lrelu + max over k' ----------------------
__global__ __launch_bounds__(256) void conv1_k(const float* __restrict__ xt1p,
    const int* __restrict__ idx1, const float* __restrict__ w1,
    const float* __restrict__ bg, const float* __restrict__ bb,
    float* __restrict__ x1g) {
  __shared__ float wt[108][64];
  __shared__ float cwt[36][64];
  __shared__ __align__(16) float yfl[4][10][3][20];
  __shared__ float ycl[4][10][4];
  int t = threadIdx.x;
  int fp = blockIdx.y, b = blockIdx.z;
  int np0 = blockIdx.x * 16;
  int o = t & 63, part = t >> 6;
  for (int i = part; i < 108; i += 4) {
    int w3 = i % 3, rh = i / 3;
    int cc = rh / 12, dh = rh % 12;
    wt[i][o] = w1[o * 216 + cc * 36 + dh * 3 + w3];
  }
  for (int i = part; i < 36; i += 4) {
    int cc = i / 12, dh = i % 12;
    const float* ww = &w1[o * 216 + (cc + 3) * 36 + dh * 3];
    cwt[i][o] = ww[0] + ww[1] + ww[2];
  }
  int g2 = b * 8 + fp;
  for (int rnd = 0; rnd < 4; ++rnd) {
    int npr = np0 + rnd * 4;
    __syncthreads();
    for (int it = t; it < 800; it += 256) {
      int d = it / 200, rem = it % 200, nl = rem / 20, k = rem % 20;
      int n = 2 * npr + nl;
      if (n < 512) {
        int g = b * 32 + fp * 4 + d;
        int j = idx1[((size_t)g * 512 + n) * 20 + k];
        f4 vj = *(const f4*)(xt1p + ((size_t)g * 512 + j) * 4);
        f4 vc = *(const f4*)(xt1p + ((size_t)g * 512 + n) * 4);
        yfl[d][nl][0][k] = vj[0] - vc[0];
        yfl[d][nl][1][k] = vj[1] - vc[1];
        yfl[d][nl][2][k] = vj[2] - vc[2];
      } else {
        yfl[d][nl][0][k] = 0.f; yfl[d][nl][1][k] = 0.f; yfl[d][nl][2][k] = 0.f;
      }
    }
    if (t < 40) {
      int d = t / 10, nl = t % 10;
      int n = 2 * npr + nl;
      if (n < 512) {
        int g = b * 32 + fp * 4 + d;
        f4 vc = *(const f4*)(xt1p + ((size_t)g * 512 + n) * 4);
        ycl[d][nl][0] = vc[0]; ycl[d][nl][1] = vc[1]; ycl[d][nl][2] = vc[2];
      } else {
        ycl[d][nl][0] = 0.f; ycl[d][nl][1] = 0.f; ycl[d][nl][2] = 0.f;
      }
    }
    __syncthreads();
    int np = npr + part;
    if (np < 255) {
      float fa[18] = {0.f,0.f,0.f,0.f,0.f,0.f,0.f,0.f,0.f,
                      0.f,0.f,0.f,0.f,0.f,0.f,0.f,0.f,0.f};
      float ctr = 0.f;
      for (int cc = 0; cc < 3; ++cc) {
        for (int dh = 0; dh < 12; ++dh) {
          int d = dh / 3, h = dh % 3;
          int nl = 2 * part + h;
          int ib = (cc * 12 + dh) * 3;
          float w0 = wt[ib][o], w1v = wt[ib + 1][o], w2v = wt[ib + 2][o];
          ctr += ycl[d][nl][cc] * cwt[cc * 12 + dh][o];
          const f4* yr = (const f4*)&yfl[d][nl][cc][0];
          float y[20];
#pragma unroll
          for (int q = 0; q < 5; ++q) {
            f4 v = yr[q];
            y[4*q+0] = v[0]; y[4*q+1] = v[1]; y[4*q+2] = v[2]; y[4*q+3] = v[3];
          }
#pragma unroll
          for (int kp = 0; kp < 18; ++kp)
            fa[kp] += w0 * y[kp] + w1v * y[kp + 1] + w2v * y[kp + 2];
        }
      }
      float vmax = fa[0];
#pragma unroll
      for (int kp = 1; kp < 18; ++kp) vmax = fmaxf(vmax, fa[kp]);
      vmax += ctr;
      float sc = bg[o] / sqrtf(1.0f + BN_EPS);
      float z = sc * vmax + bb[o];
      if (z < 0.f) z *= NEG;
      x1g[((size_t)g2 * 255 + np) * 64 + o] = z;
    }
  }
}

// ---------------- Stage 2: q2,k2,v2 (32 rows/block) ----------------------
__global__ __launch_bounds__(256) void qkv2_k(const float* __restrict__ x1g,
    const float* __restrict__ Wq, const float* __restrict__ Wk, const float* __restrict__ Wv,
    float* __restrict__ q2, float* __restrict__ k2, float* __restrict__ v2) {
  __shared__ float Wl[3][64 * 65];
  __shared__ float rowl[4][64];
  int t = threadIdx.x, g = blockIdx.y;
  int w = t >> 6, l = t & 63;
  for (int i = t; i < 4096; i += 256) {
    int r = i >> 6, c = i & 63;
    Wl[0][r * 65 + c] = Wq[i];
    Wl[1][r * 65 + c] = Wk[i];
    Wl[2][r * 65 + c] = Wv[i];
  }
  __syncthreads();
  for (int rr = 0; rr < 8; ++rr) {
    int n = blockIdx.x * 32 + rr * 4 + w;
    bool valid = n < 255;
    rowl[w][l] = valid ? x1g[((size_t)g * 255 + n) * 64 + l] : 0.f;
    float qa = 0.f, ka = 0.f, va = 0.f;
    for (int c = 0; c < 64; ++c) {
      float rv = rowl[w][c];
      qa += rv * Wl[0][l * 65 + c];
      ka += rv * Wl[1][l * 65 + c];
      va += rv * Wl[2][l * 65 + c];
    }
    if (valid) {
      size_t off = ((size_t)g * 255 + n) * 64 + l;
      q2[off] = qa; k2[off] = ka; v2[off] = va;
    }
  }
}

// ---------------- Stage 2 attention: xt2, idx2 (64 rows/block) -----------
__global__ __launch_bounds__(512, 2) void attn2_k(const float* __restrict__ q2,
    const float* __restrict__ k2, const float* __restrict__ v2,
    const float* __restrict__ x1g, float* __restrict__ xt2, int* __restrict__ idx2) {
  __shared__ __align__(16) float Kl[255 * 64];   // word: m*64 + (c4^((m&7)<<2))
  __shared__ __align__(16) float Vl[255 * 64];   // linear [m][c]
  __shared__ __align__(16) float pl[8][2][256];  // [wave][row][m] (m=255 -> 0)
  __shared__ __align__(16) float ql[8][2][64];
  int t = threadIdx.x, g = blockIdx.x;
  int w = t >> 6, l = t & 63;
  int n0 = blockIdx.y * 64;
  const float* kg = k2 + (size_t)g * 16320;
  const float* vg = v2 + (size_t)g * 16320;
#pragma unroll 2
  for (int i = t; i < 4080; i += 512) {
    int m = i >> 4, c4 = (i & 15) << 2;
    f4 kv = *(const f4*)(kg + (size_t)i * 4);
    f4 vv = *(const f4*)(vg + (size_t)i * 4);
    *(f4*)&Kl[m * 64 + (c4 ^ ((m & 7) << 2))] = kv;
    *(f4*)&Vl[m * 64 + c4] = vv;
  }
  __syncthreads();
  for (int grp = 0; grp < 4; ++grp) {
    int rbase = n0 + w * 8 + grp * 2;
#pragma unroll
    for (int r = 0; r < 2; ++r) {
      int n = rbase + r;
      ql[w][r][l] = (n < 255) ? q2[((size_t)g * 255 + n) * 64 + l] : 0.f;
    }
    float s[2][4] = {};
#pragma unroll 2
    for (int c4 = 0; c4 < 64; c4 += 4) {
      f4 kv[4];
#pragma unroll
      for (int j = 0; j < 4; ++j) {
        int m = l + 64 * j;
        kv[j] = *(const f4*)&Kl[m * 64 + (c4 ^ ((m & 7) << 2))];
      }
#pragma unroll
      for (int r = 0; r < 2; ++r) {
        f4 qv = *(const f4*)&ql[w][r][c4];
#pragma unroll
        for (int j = 0; j < 4; ++j)
          s[r][j] += qv[0]*kv[j][0] + qv[1]*kv[j][1] + qv[2]*kv[j][2] + qv[3]*kv[j][3];
      }
    }
    unsigned Hi[2][4], Lo[2][4];
#pragma unroll
    for (int r = 0; r < 2; ++r) {
#pragma unroll
      for (int j = 0; j < 4; ++j) s[r][j] = s[r][j] / 8.0f;
      if (l == 63) s[r][3] = -1e30f;              // m = 255 invalid
      float mx = fmaxf(fmaxf(s[r][0], s[r][1]), fmaxf(s[r][2], s[r][3]));
      mx = wred_max_f32(mx);
      float ws = 0.f;
#pragma unroll
      for (int j = 0; j < 4; ++j) { s[r][j] = expf(s[r][j] - mx); ws += s[r][j]; }
      ws = wred_sum_f32(ws);
      unsigned long long key[4];
#pragma unroll
      for (int j = 0; j < 4; ++j) {
        s[r][j] = s[r][j] / ws;
        pl[w][r][64 * j + l] = s[r][j];
        key[j] = ((unsigned long long)__float_as_uint(s[r][j]) << 32)
               | (unsigned)(~(unsigned)(64 * j + l));
      }
      CE(key,0,1) CE(key,2,3) CE(key,0,2) CE(key,1,3) CE(key,1,2)
#pragma unroll
      for (int j = 0; j < 4; ++j) {
        Hi[r][j] = (unsigned)(key[j] >> 32); Lo[r][j] = (unsigned)key[j];
      }
    }
    float acc[2] = {0.f, 0.f};
#pragma unroll 4
    for (int m4 = 0; m4 < 256; m4 += 4) {
      f4 pv[2];
#pragma unroll
      for (int r = 0; r < 2; ++r) pv[r] = *(const f4*)&pl[w][r][m4];
      float v0 = Vl[(m4 + 0) * 64 + l];
      float v1 = Vl[(m4 + 1) * 64 + l];
      float v2v = Vl[(m4 + 2) * 64 + l];
      float v3 = Vl[(m4 + 3) * 64 + l];
#pragma unroll
      for (int r = 0; r < 2; ++r)
        acc[r] += pv[r][0]*v0 + pv[r][1]*v1 + pv[r][2]*v2v + pv[r][3]*v3;
    }
#pragma unroll
    for (int r = 0; r < 2; ++r) {
      int n = rbase + r;
      if (n < 255) {
        size_t off = ((size_t)g * 255 + n) * 64 + l;
        xt2[off] = x1g[off] + acc[r];
      }
    }
    int* io0 = idx2 + ((size_t)g * 255 + rbase + 0) * 20;
    int* io1 = idx2 + ((size_t)g * 255 + rbase + 1) * 20;
    for (int kk = 0; kk < 20; ++kk) {
      unsigned g0 = sel_round4(Hi[0], Lo[0], kk < 19);
      unsigned g1 = sel_round4(Hi[1], Lo[1], kk < 19);
      if (l == 0) {
        if (rbase + 0 < 255) io0[kk] = (int)(~g0);
        if (rbase + 1 < 255) io1[kk] = (int)(~g1);
      }
    }
  }
}

// ---------------- w2 transpose: w2T[c][o] --------------------------------
__global__ __launch_bounds__(256) void w2t_k(const float* __restrict__ w2,
                                             float* __restrict__ w2T) {
  int t = threadIdx.x;
  for (int i = t; i < 16384; i += 256) {
    int o = i >> 7, c = i & 127;
    w2T[c * 128 + o] = w2[o * 128 + c];
  }
}

// ---------------- conv2 (1x1, 128x128) + bn2 + lrelu + max over k --------
// 4 positions/block, 128 threads -> LDS 21.5KB -> ~7 blocks/CU (latency
// hiding). Weights from global w2T (L1/L2-hot). Same per-thread c-loops
// as r18/r19 -> bit-identical sums.
__global__ __launch_bounds__(128) void conv2_k(const float* __restrict__ xt2,
    const int* __restrict__ idx2, const float* __restrict__ w2T,
    const float* __restrict__ bg, const float* __restrict__ bb,
    float* __restrict__ x2g) {
  __shared__ __align__(16) float rowsT[4][64][20];  // [pos][c][k]
  __shared__ float ctr2[4][64];                     // [pos][c]
  int t = threadIdx.x, g = blockIdx.y;
  int n0 = blockIdx.x * 4;
  for (int i = t; i < 5120; i += 128) {
    int pos = i / 1280, rem = i % 1280, k = rem >> 6, c = rem & 63;
    int n = n0 + pos;
    float v = 0.f;
    if (n < 255) {
      int j = idx2[((size_t)g * 255 + n) * 20 + k];
      v = xt2[((size_t)g * 255 + j) * 64 + c];
    }
    rowsT[pos][c][k] = v;
  }
  for (int i = t; i < 256; i += 128) {
    int pos = i >> 6, c = i & 63;
    int n = n0 + pos;
    ctr2[pos][c] = (n < 255) ? xt2[((size_t)g * 255 + n) * 64 + c] : 0.f;
  }
  __syncthreads();
  int os = t & 31, np = t >> 5;   // np in 0..3
  float acc[4][20] = {};
  float t1[4] = {0.f, 0.f, 0.f, 0.f};
  for (int c = 0; c < 64; ++c) {
    f4 wq = *(const f4*)(w2T + c * 128 + os * 4);
    float cv = ctr2[np][c];
#pragma unroll
    for (int i = 0; i < 4; ++i) t1[i] += wq[i] * cv;
#pragma unroll
    for (int q = 0; q < 5; ++q) {
      f4 rv = *(const f4*)&rowsT[np][c][4 * q];
#pragma unroll
      for (int e = 0; e < 4; ++e)
#pragma unroll
        for (int i = 0; i < 4; ++i) acc[i][4 * q + e] += wq[i] * rv[e];
    }
  }
  float t2[4] = {0.f, 0.f, 0.f, 0.f};
  for (int c = 0; c < 64; ++c) {
    f4 wq = *(const f4*)(w2T + (64 + c) * 128 + os * 4);
    float cv = ctr2[np][c];
#pragma unroll
    for (int i = 0; i < 4; ++i) t2[i] += wq[i] * cv;
  }
  int n = n0 + np;
  f4 res;
#pragma unroll
  for (int i = 0; i < 4; ++i) {
    float vm = -1e30f;
#pragma unroll
    for (int j = 0; j < 20; ++j) vm = fmaxf(vm, acc[i][j]);
    vm += t2[i] - t1[i];
    int o = os * 4 + i;
    float sc = bg[o] / sqrtf(1.0f + BN_EPS);
    float z = sc * vm + bb[o];
    if (z < 0.f) z *= NEG;
    res[i] = z;
  }
  if (n < 255)
    *(f4*)&x2g[((size_t)g * 255 + n) * 128 + os * 4] = res;
}

// ---------------- conv5 (1x1, 1024x192) + bn5 + lrelu + max over n -------
// r14 body; red[] aliased onto colhT (dead by then; extra barrier added).
// LDS 54,784 -> 50,688 B: crosses the 3-blocks/CU threshold.
__global__ __launch_bounds__(256) void conv5_k(const float* __restrict__ x1g,
    const float* __restrict__ x2g, const float* __restrict__ w5,
    const float* __restrict__ bg, const float* __restrict__ bb,
    float* __restrict__ out, int ot0) {
  __shared__ __align__(16) float w5h[96 * 64];
  __shared__ __align__(16) float colhT[96][68];   // [c][n(64)+pad]
  float (*red)[64] = (float (*)[64])&colhT[0][0]; // overlay (colhT dead)
  int t = threadIdx.x;
  int px = blockIdx.x, ot = blockIdx.y + ot0;
  int fp = px & 7, b = px >> 3;
  size_t rowbase = ((size_t)b * 8 + fp) * 255;
  int os = t & 15, ns = t >> 4;
  float acc[4][4][4] = {};   // [grp][o4][n4]
  for (int ch = 0; ch < 2; ++ch) {
    __syncthreads();
    for (int i = t; i < 6144; i += 256) {
      int oL = i / 96, c = i % 96;
      w5h[c * 64 + (oL ^ (c & 28))] = w5[((size_t)(ot * 64 + oL)) * 192 + ch * 96 + c];
    }
#pragma unroll
    for (int grp = 0; grp < 4; ++grp) {
      __syncthreads();
      for (int i = t; i < 6144; i += 256) {
        int nl = i / 96, c = i % 96;
        int n = grp * 64 + nl;
        float v = 0.f;
        if (n < 255) {
          int cc = ch * 96 + c;
          v = (cc < 64) ? x1g[(rowbase + n) * 64 + cc]
                        : x2g[(rowbase + n) * 128 + (cc - 64)];
        }
        colhT[c][nl] = v;
      }
      __syncthreads();
      for (int c = 0; c < 96; ++c) {
        f4 wq = *(const f4*)&w5h[c * 64 + ((os * 4) ^ (c & 28))];
        f4 cv = *(const f4*)&colhT[c][ns * 4];
#pragma unroll
        for (int u = 0; u < 4; ++u)
#pragma unroll
          for (int vv = 0; vv < 4; ++vv) acc[grp][u][vv] += wq[u] * cv[vv];
      }
    }
  }
  float vm[4] = {-1e30f, -1e30f, -1e30f, -1e30f};
#pragma unroll
  for (int grp = 0; grp < 4; ++grp)
#pragma unroll
    for (int vv = 0; vv < 4; ++vv) {
      int n = grp * 64 + ns * 4 + vv;
      if (n < 255)
#pragma unroll
        for (int u = 0; u < 4; ++u) vm[u] = fmaxf(vm[u], acc[grp][u][vv]);
    }
  __syncthreads();                 // colhT fully dead before red overlay
#pragma unroll
  for (int u = 0; u < 4; ++u) red[ns][os * 4 + u] = vm[u];
  __syncthreads();
  if (t < 64) {
    float m = -1e30f;
#pragma unroll
    for (int q = 0; q < 16; ++q) m = fmaxf(m, red[q][t]);
    int o = ot * 64 + t;
    float sc = bg[o] / sqrtf(1.0f + BN_EPS);
    float z = sc * m + bb[o];
    if (z < 0.f) z *= NEG;
    out[((size_t)b * 8 + fp) * 1024 + o] = z;
  }
}

// ---------------- launcher ----------------------------------------------
extern "C" void kernel_launch(void* const* d_in, const int* in_sizes, int n_in,
                              void* d_out, int out_size, void* d_ws, size_t ws_size,
                              hipStream_t stream) {
  const float* x   = (const float*)d_in[0];
  const float* Wq1 = (const float*)d_in[1];
  const float* Wk1 = (const float*)d_in[2];
  const float* Wv1 = (const float*)d_in[3];
  const float* Wq2 = (const float*)d_in[4];
  const float* Wk2 = (const float*)d_in[5];
  const float* Wv2 = (const float*)d_in[6];
  const float* w1  = (const float*)d_in[7];
  const float* w2  = (const float*)d_in[8];
  const float* w5  = (const float*)d_in[9];
  const float* bg1 = (const float*)d_in[10];
  const float* bb1 = (const float*)d_in[11];
  const float* bg2 = (const float*)d_in[12];
  const float* bb2 = (const float*)d_in[13];
  const float* bg5 = (const float*)d_in[14];
  const float* bb5 = (const float*)d_in[15];
  float* out = (float*)d_out;
  float* ws  = (float*)d_ws;

  float* x1g  = ws;                       // 1044480
  float* xt1p = ws + 1048576;             // 524288
  int*   idx1 = (int*)(ws + 1572864);     // 2621440
  float* q2   = ws + 4194304;             // 1044480
  float* k2   = ws + 5238784;             // 1044480
  float* v2   = ws + 6283264;             // 1044480
  float* xt2  = ws + 7327744;             // 1044480
  int*   idx2 = (int*)(ws + 8372224);     // 326400
  float* x2g  = ws + 8698624;             // 2088960
  float* w2T  = ws + 10787584;            // 16384

  attn1_k<<<dim3(32, 64), 256, 0, stream>>>(x, Wq1, Wk1, Wv1, xt1p, idx1, 0);
  attn1_k<<<dim3(32, 64), 256, 0, stream>>>(x, Wq1, Wk1, Wv1, xt1p, idx1, 64);
  attn1_k<<<dim3(32, 64), 256, 0, stream>>>(x, Wq1, Wk1, Wv1, xt1p, idx1, 128);
  attn1_k<<<dim3(32, 64), 256, 0, stream>>>(x, Wq1, Wk1, Wv1, xt1p, idx1, 192);
  conv1_k<<<dim3(16, 8, 8), 256, 0, stream>>>(xt1p, idx1, w1, bg1, bb1, x1g);
  qkv2_k<<<dim3(8, 64), 256, 0, stream>>>(x1g, Wq2, Wk2, Wv2, q2, k2, v2);
  attn2_k<<<dim3(64, 4), 512, 0, stream>>>(q2, k2, v2, x1g, xt2, idx2);
  w2t_k<<<dim3(1), 256, 0, stream>>>(w2, w2T);
  conv2_k<<<dim3(64, 64), 128, 0, stream>>>(xt2, idx2, w2T, bg2, bb2, x2g);
  conv5_k<<<dim3(64, 8), 256, 0, stream>>>(x1g, x2g, w5, bg5, bb5, out, 0);
  conv5_k<<<dim3(64, 8), 256, 0, stream>>>(x1g, x2g, w5, bg5, bb5, out, 8);
}

// Round 21
// 749.371 us; speedup vs baseline: 1.0713x; 1.0408x over previous
//
#include <hip/hip_runtime.h>
#include <hip/hip_bf16.h>
#include <math.h>

typedef float f4 __attribute__((ext_vector_type(4)));

#define NEG 0.2f
#define BN_EPS 1e-5f

// compare-exchange on u64 keys, descending (larger first)
#define CE(K,A,B) { unsigned long long _x = K[A], _y = K[B]; bool _s = _x < _y; \
                    K[A] = _s ? _y : _x; K[B] = _s ? _x : _y; }

// ---- wave-64 reductions via DPP (VALU pipe, no ds_bpermute) -------------
__device__ __forceinline__ float wred_max_f32(float v) {
  int x = __float_as_int(v), y;
#define STEPM(C) y = __builtin_amdgcn_update_dpp(x, x, C, 0xf, 0xf, false); \
  x = __float_as_int(fmaxf(__int_as_float(x), __int_as_float(y)));
  STEPM(0x111) STEPM(0x112) STEPM(0x114) STEPM(0x118) STEPM(0x142) STEPM(0x143)
#undef STEPM
  return __int_as_float(__builtin_amdgcn_readlane(x, 63));
}
__device__ __forceinline__ float wred_sum_f32(float v) {
  int x = __float_as_int(v), y;
#define STEPS(C) y = __builtin_amdgcn_update_dpp(0, x, C, 0xf, 0xf, true); \
  x = __float_as_int(__int_as_float(x) + __int_as_float(y));
  STEPS(0x111) STEPS(0x112) STEPS(0x114) STEPS(0x118) STEPS(0x142) STEPS(0x143)
#undef STEPS
  return __int_as_float(__builtin_amdgcn_readlane(x, 63));
}
// u32 max: 4 DPP steps (per-16 prefix max) + 4 readlane + SALU max tree.
__device__ __forceinline__ unsigned wred16_max_u32(unsigned v) {
  int x = (int)v, y;
#define STEPU(C) y = __builtin_amdgcn_update_dpp(x, x, C, 0xf, 0xf, false); \
  x = (int)((unsigned)x > (unsigned)y ? (unsigned)x : (unsigned)y);
  STEPU(0x111) STEPU(0x112) STEPU(0x114) STEPU(0x118)
#undef STEPU
  unsigned a0 = (unsigned)__builtin_amdgcn_readlane(x, 15);
  unsigned a1 = (unsigned)__builtin_amdgcn_readlane(x, 31);
  unsigned a2 = (unsigned)__builtin_amdgcn_readlane(x, 47);
  unsigned a3 = (unsigned)__builtin_amdgcn_readlane(x, 63);
  unsigned m01 = a0 > a1 ? a0 : a1;
  unsigned m23 = a2 > a3 ? a2 : a3;
  return m01 > m23 ? m01 : m23;
}

__device__ __forceinline__ unsigned sel_round4(unsigned (&hi)[4], unsigned (&lo)[4],
                                               bool do_pop) {
  unsigned gv = wred16_max_u32(hi[0]);
  unsigned long long tied = __ballot(hi[0] == gv);
  unsigned gl;
  if (__popcll(tied) == 1) {
    int wl = __ffsll((long long)tied) - 1;
    gl = (unsigned)__builtin_amdgcn_readlane((int)lo[0], wl);
  } else {
    gl = wred16_max_u32((hi[0] == gv) ? lo[0] : 0u);
  }
  if (do_pop) {
    bool win = (hi[0] == gv) && (lo[0] == gl);
    hi[0] = win ? hi[1] : hi[0]; lo[0] = win ? lo[1] : lo[0];
    hi[1] = win ? hi[2] : hi[1]; lo[1] = win ? lo[2] : lo[1];
    hi[2] = win ? hi[3] : hi[2]; lo[2] = win ? lo[3] : lo[2];
    hi[3] = win ? 0u    : hi[3]; lo[3] = win ? 0u    : lo[3];
  }
  return gl;
}

// ---------------- Stage 1 attention (qkv fused): xt1, idx1 ----------------
__global__ __launch_bounds__(256) void attn1_k(const float* __restrict__ x,
    const float* __restrict__ Wq, const float* __restrict__ Wk,
    const float* __restrict__ Wv, float* __restrict__ xt1p, int* __restrict__ idx1,
    int g0) {
  __shared__ f4 kl[512];
  __shared__ f4 vl[512];
  __shared__ unsigned long long lists[4][2][6][64];  // [wave][pair][slot][lane]
  int t = threadIdx.x, g = blockIdx.y + g0;
  int w = t >> 6, l = t & 63;
  int nb = blockIdx.x * 16;
  const float* xr = x + (size_t)g * 1536;
  {
#pragma clang fp contract(off)
    for (int i = t; i < 512; i += 256) {
      float x0 = xr[i], x1v = xr[512 + i], x2v = xr[1024 + i];
      f4 kd, vd;
#pragma unroll
      for (int o = 0; o < 3; ++o) {
        kd[o] = x0 * Wk[o*3+0] + x1v * Wk[o*3+1] + x2v * Wk[o*3+2];
        vd[o] = x0 * Wv[o*3+0] + x1v * Wv[o*3+1] + x2v * Wv[o*3+2];
      }
      kd[3] = 0.f; vd[3] = 0.f;
      kl[i] = kd; vl[i] = vd;
    }
  }
  __syncthreads();
  for (int rp = 0; rp < 2; ++rp) {
    int nA = nb + rp * 8 + w;
    int nB = nA + 4;
    float xA0 = xr[nA], xA1 = xr[512 + nA], xA2 = xr[1024 + nA];
    float xB0 = xr[nB], xB1 = xr[512 + nB], xB2 = xr[1024 + nB];
    float qA0, qA1, qA2, qB0, qB1, qB2;
    float aA[8], aB[8];
    {
#pragma clang fp contract(off)
      qA0 = xA0*Wq[0] + xA1*Wq[1] + xA2*Wq[2];
      qA1 = xA0*Wq[3] + xA1*Wq[4] + xA2*Wq[5];
      qA2 = xA0*Wq[6] + xA1*Wq[7] + xA2*Wq[8];
      qB0 = xB0*Wq[0] + xB1*Wq[1] + xB2*Wq[2];
      qB1 = xB0*Wq[3] + xB1*Wq[4] + xB2*Wq[5];
      qB2 = xB0*Wq[6] + xB1*Wq[7] + xB2*Wq[8];
#pragma unroll
      for (int j = 0; j < 8; ++j) {
        f4 kk = kl[l + 64 * j];
        aA[j] = (qA0*kk[0] + qA1*kk[1] + qA2*kk[2]) / sqrtf(3.0f);
        aB[j] = (qB0*kk[0] + qB1*kk[1] + qB2*kk[2]) / sqrtf(3.0f);
      }
    }
    float mxA = aA[0], mxB = aB[0];
#pragma unroll
    for (int j = 1; j < 8; ++j) { mxA = fmaxf(mxA, aA[j]); mxB = fmaxf(mxB, aB[j]); }
    mxA = wred_max_f32(mxA); mxB = wred_max_f32(mxB);
    float wsA = 0.f, wsB = 0.f;
#pragma unroll
    for (int j = 0; j < 8; ++j) {
      aA[j] = expf(aA[j] - mxA); wsA += aA[j];
      aB[j] = expf(aB[j] - mxB); wsB += aB[j];
    }
    wsA = wred_sum_f32(wsA); wsB = wred_sum_f32(wsB);
#pragma unroll
    for (int j = 0; j < 8; ++j) { aA[j] = aA[j] / wsA; aB[j] = aB[j] / wsB; }
    float oA0 = 0.f, oA1 = 0.f, oA2 = 0.f, oB0 = 0.f, oB1 = 0.f, oB2 = 0.f;
#pragma unroll
    for (int j = 0; j < 8; ++j) {
      f4 vv = vl[l + 64 * j];
      oA0 += aA[j] * vv[0]; oA1 += aA[j] * vv[1]; oA2 += aA[j] * vv[2];
      oB0 += aB[j] * vv[0]; oB1 += aB[j] * vv[1]; oB2 += aB[j] * vv[2];
    }
    oA0 = wred_sum_f32(oA0); oA1 = wred_sum_f32(oA1); oA2 = wred_sum_f32(oA2);
    oB0 = wred_sum_f32(oB0); oB1 = wred_sum_f32(oB1); oB2 = wred_sum_f32(oB2);
    if (l == 0) {
      float* xo = xt1p + ((size_t)g * 512 + nA) * 4;
      xo[0] = xA0 + oA0; xo[1] = xA1 + oA1; xo[2] = xA2 + oA2;
      float* xo2 = xt1p + ((size_t)g * 512 + nB) * 4;
      xo2[0] = xB0 + oB0; xo2[1] = xB1 + oB1; xo2[2] = xB2 + oB2;
    }
    // ---- keys + per-lane sort ----
    unsigned long long keyA[8], keyB[8];
#pragma unroll
    for (int j = 0; j < 8; ++j) {
      unsigned idx = (unsigned)(l + 64 * j);
      keyA[j] = ((unsigned long long)__float_as_uint(aA[j]) << 32) | (unsigned)(~idx);
      keyB[j] = ((unsigned long long)__float_as_uint(aB[j]) << 32) | (unsigned)(~idx);
    }
    CE(keyA,0,1) CE(keyA,2,3) CE(keyA,4,5) CE(keyA,6,7)
    CE(keyA,0,2) CE(keyA,1,3) CE(keyA,4,6) CE(keyA,5,7)
    CE(keyA,1,2) CE(keyA,5,6)
    CE(keyA,0,4) CE(keyA,1,5) CE(keyA,2,6) CE(keyA,3,7)
    CE(keyA,2,4) CE(keyA,3,5)
    CE(keyA,1,2) CE(keyA,3,4) CE(keyA,5,6)
    CE(keyB,0,1) CE(keyB,2,3) CE(keyB,4,5) CE(keyB,6,7)
    CE(keyB,0,2) CE(keyB,1,3) CE(keyB,4,6) CE(keyB,5,7)
    CE(keyB,1,2) CE(keyB,5,6)
    CE(keyB,0,4) CE(keyB,1,5) CE(keyB,2,6) CE(keyB,3,7)
    CE(keyB,2,4) CE(keyB,3,5)
    CE(keyB,1,2) CE(keyB,3,4) CE(keyB,5,6)
    // spill slots 2..7 (slot-major: conflict-free); no sentinel slot
#pragma unroll
    for (int j = 2; j < 8; ++j) {
      lists[w][0][j - 2][l] = keyA[j];
      lists[w][1][j - 2][l] = keyB[j];
    }
    unsigned hHiA = (unsigned)(keyA[0] >> 32), hLoA = (unsigned)keyA[0];
    unsigned nHiA = (unsigned)(keyA[1] >> 32), nLoA = (unsigned)keyA[1];
    unsigned hHiB = (unsigned)(keyB[0] >> 32), hLoB = (unsigned)keyB[0];
    unsigned nHiB = (unsigned)(keyB[1] >> 32), nLoB = (unsigned)keyB[1];
    int slA = 0, slB = 0;
    unsigned long long pfA = lists[w][0][0][l], pfB = lists[w][1][0][l];
    int* ioA = idx1 + ((size_t)g * 512 + nA) * 20;
    int* ioB = idx1 + ((size_t)g * 512 + nB) * 20;
    for (int kk = 0; kk < 20; ++kk) {
      unsigned gvA = wred16_max_u32(hHiA);
      unsigned gvB = wred16_max_u32(hHiB);
      unsigned long long mA = __ballot(hHiA == gvA);
      unsigned long long mB = __ballot(hHiB == gvB);
      unsigned glA, glB;
      if (__popcll(mA) == 1) {
        int wl = __ffsll((long long)mA) - 1;
        glA = (unsigned)__builtin_amdgcn_readlane((int)hLoA, wl);
      } else glA = wred16_max_u32((hHiA == gvA) ? hLoA : 0u);
      if (__popcll(mB) == 1) {
        int wl = __ffsll((long long)mB) - 1;
        glB = (unsigned)__builtin_amdgcn_readlane((int)hLoB, wl);
      } else glB = wred16_max_u32((hHiB == gvB) ? hLoB : 0u);
      if (l == 0) { ioA[kk] = (int)(~glA); ioB[kk] = (int)(~glB); }
      if (kk < 19) {
        bool wA = (hHiA == gvA) && (hLoA == glA);
        hHiA = wA ? nHiA : hHiA; hLoA = wA ? nLoA : hLoA;
        nHiA = wA ? (unsigned)(pfA >> 32) : nHiA;
        nLoA = wA ? (unsigned)pfA : nLoA;
        slA = wA ? slA + 1 : slA;
        {
          int ixA = slA > 5 ? 5 : slA;
          unsigned long long rdA = lists[w][0][ixA][l];
          pfA = (slA > 5) ? 0ull : rdA;
        }
        bool wB = (hHiB == gvB) && (hLoB == glB);
        hHiB = wB ? nHiB : hHiB; hLoB = wB ? nLoB : hLoB;
        nHiB = wB ? (unsigned)(pfB >> 32) : nHiB;
        nLoB = wB ? (unsigned)pfB : nLoB;
        slB = wB ? slB + 1 : slB;
        {
          int ixB = slB > 5 ? 5 : slB;
          unsigned long long rdB = lists[w][1][ixB][l];
          pfB = (slB > 5) ? 0ull : rdB;
        }
      }
    }
  }
}

// ---------------- conv1 + bn1 + lrelu + max over k' ----------------------
__global__ __launch_bounds__(256) void conv1_k(const float* __restrict__ xt1p,
    const int* __restrict__ idx1, const float* __restrict__ w1,
    const float* __restrict__ bg, const float* __restrict__ bb,
    float* __restrict__ x1g) {
  __shared__ float wt[108][64];
  __shared__ float cwt[36][64];
  __shared__ __align__(16) float yfl[4][10][3][20];
  __shared__ float ycl[4][10][4];
  int t = threadIdx.x;
  int fp = blockIdx.y, b = blockIdx.z;
  int np0 = blockIdx.x * 16;
  int o = t & 63, part = t >> 6;
  for (int i = part; i < 108; i += 4) {
    int w3 = i % 3, rh = i / 3;
    int cc = rh / 12, dh = rh % 12;
    wt[i][o] = w1[o * 216 + cc * 36 + dh * 3 + w3];
  }
  for (int i = part; i < 36; i += 4) {
    int cc = i / 12, dh = i % 12;
    const float* ww = &w1[o * 216 + (cc + 3) * 36 + dh * 3];
    cwt[i][o] = ww[0] + ww[1] + ww[2];
  }
  int g2 = b * 8 + fp;
  for (int rnd = 0; rnd < 4; ++rnd) {
    int npr = np0 + rnd * 4;
    __syncthreads();
    for (int it = t; it < 800; it += 256) {
      int d = it / 200, rem = it % 200, nl = rem / 20, k = rem % 20;
      int n = 2 * npr + nl;
      if (n < 512) {
        int g = b * 32 + fp * 4 + d;
        int j = idx1[((size_t)g * 512 + n) * 20 + k];
        f4 vj = *(const f4*)(xt1p + ((size_t)g * 512 + j) * 4);
        f4 vc = *(const f4*)(xt1p + ((size_t)g * 512 + n) * 4);
        yfl[d][nl][0][k] = vj[0] - vc[0];
        yfl[d][nl][1][k] = vj[1] - vc[1];
        yfl[d][nl][2][k] = vj[2] - vc[2];
      } else {
        yfl[d][nl][0][k] = 0.f; yfl[d][nl][1][k] = 0.f; yfl[d][nl][2][k] = 0.f;
      }
    }
    if (t < 40) {
      int d = t / 10, nl = t % 10;
      int n = 2 * npr + nl;
      if (n < 512) {
        int g = b * 32 + fp * 4 + d;
        f4 vc = *(const f4*)(xt1p + ((size_t)g * 512 + n) * 4);
        ycl[d][nl][0] = vc[0]; ycl[d][nl][1] = vc[1]; ycl[d][nl][2] = vc[2];
      } else {
        ycl[d][nl][0] = 0.f; ycl[d][nl][1] = 0.f; ycl[d][nl][2] = 0.f;
      }
    }
    __syncthreads();
    int np = npr + part;
    if (np < 255) {
      float fa[18] = {0.f,0.f,0.f,0.f,0.f,0.f,0.f,0.f,0.f,
                      0.f,0.f,0.f,0.f,0.f,0.f,0.f,0.f,0.f};
      float ctr = 0.f;
      for (int cc = 0; cc < 3; ++cc) {
        for (int dh = 0; dh < 12; ++dh) {
          int d = dh / 3, h = dh % 3;
          int nl = 2 * part + h;
          int ib = (cc * 12 + dh) * 3;
          float w0 = wt[ib][o], w1v = wt[ib + 1][o], w2v = wt[ib + 2][o];
          ctr += ycl[d][nl][cc] * cwt[cc * 12 + dh][o];
          const f4* yr = (const f4*)&yfl[d][nl][cc][0];
          float y[20];
#pragma unroll
          for (int q = 0; q < 5; ++q) {
            f4 v = yr[q];
            y[4*q+0] = v[0]; y[4*q+1] = v[1]; y[4*q+2] = v[2]; y[4*q+3] = v[3];
          }
#pragma unroll
          for (int kp = 0; kp < 18; ++kp)
            fa[kp] += w0 * y[kp] + w1v * y[kp + 1] + w2v * y[kp + 2];
        }
      }
      float vmax = fa[0];
#pragma unroll
      for (int kp = 1; kp < 18; ++kp) vmax = fmaxf(vmax, fa[kp]);
      vmax += ctr;
      float sc = bg[o] / sqrtf(1.0f + BN_EPS);
      float z = sc * vmax + bb[o];
      if (z < 0.f) z *= NEG;
      x1g[((size_t)g2 * 255 + np) * 64 + o] = z;
    }
  }
}

// ---------------- Stage 2: q2,k2,v2 (32 rows/block) ----------------------
__global__ __launch_bounds__(256) void qkv2_k(const float* __restrict__ x1g,
    const float* __restrict__ Wq, const float* __restrict__ Wk, const float* __restrict__ Wv,
    float* __restrict__ q2, float* __restrict__ k2, float* __restrict__ v2) {
  __shared__ float Wl[3][64 * 65];
  __shared__ float rowl[4][64];
  int t = threadIdx.x, g = blockIdx.y;
  int w = t >> 6, l = t & 63;
  for (int i = t; i < 4096; i += 256) {
    int r = i >> 6, c = i & 63;
    Wl[0][r * 65 + c] = Wq[i];
    Wl[1][r * 65 + c] = Wk[i];
    Wl[2][r * 65 + c] = Wv[i];
  }
  __syncthreads();
  for (int rr = 0; rr < 8; ++rr) {
    int n = blockIdx.x * 32 + rr * 4 + w;
    bool valid = n < 255;
    rowl[w][l] = valid ? x1g[((size_t)g * 255 + n) * 64 + l] : 0.f;
    float qa = 0.f, ka = 0.f, va = 0.f;
    for (int c = 0; c < 64; ++c) {
      float rv = rowl[w][c];
      qa += rv * Wl[0][l * 65 + c];
      ka += rv * Wl[1][l * 65 + c];
      va += rv * Wl[2][l * 65 + c];
    }
    if (valid) {
      size_t off = ((size_t)g * 255 + n) * 64 + l;
      q2[off] = qa; k2[off] = ka; v2[off] = va;
    }
  }
}

// ---------------- Stage 2 attention: xt2, idx2 (64 rows/block) -----------
__global__ __launch_bounds__(512, 2) void attn2_k(const float* __restrict__ q2,
    const float* __restrict__ k2, const float* __restrict__ v2,
    const float* __restrict__ x1g, float* __restrict__ xt2, int* __restrict__ idx2) {
  __shared__ __align__(16) float Kl[255 * 64];   // word: m*64 + (c4^((m&7)<<2))
  __shared__ __align__(16) float Vl[255 * 64];   // linear [m][c]
  __shared__ __align__(16) float pl[8][2][256];  // [wave][row][m] (m=255 -> 0)
  __shared__ __align__(16) float ql[8][2][64];
  int t = threadIdx.x, g = blockIdx.x;
  int w = t >> 6, l = t & 63;
  int n0 = blockIdx.y * 64;
  const float* kg = k2 + (size_t)g * 16320;
  const float* vg = v2 + (size_t)g * 16320;
#pragma unroll 2
  for (int i = t; i < 4080; i += 512) {
    int m = i >> 4, c4 = (i & 15) << 2;
    f4 kv = *(const f4*)(kg + (size_t)i * 4);
    f4 vv = *(const f4*)(vg + (size_t)i * 4);
    *(f4*)&Kl[m * 64 + (c4 ^ ((m & 7) << 2))] = kv;
    *(f4*)&Vl[m * 64 + c4] = vv;
  }
  __syncthreads();
  for (int grp = 0; grp < 4; ++grp) {
    int rbase = n0 + w * 8 + grp * 2;
#pragma unroll
    for (int r = 0; r < 2; ++r) {
      int n = rbase + r;
      ql[w][r][l] = (n < 255) ? q2[((size_t)g * 255 + n) * 64 + l] : 0.f;
    }
    float s[2][4] = {};
#pragma unroll 2
    for (int c4 = 0; c4 < 64; c4 += 4) {
      f4 kv[4];
#pragma unroll
      for (int j = 0; j < 4; ++j) {
        int m = l + 64 * j;
        kv[j] = *(const f4*)&Kl[m * 64 + (c4 ^ ((m & 7) << 2))];
      }
#pragma unroll
      for (int r = 0; r < 2; ++r) {
        f4 qv = *(const f4*)&ql[w][r][c4];
#pragma unroll
        for (int j = 0; j < 4; ++j)
          s[r][j] += qv[0]*kv[j][0] + qv[1]*kv[j][1] + qv[2]*kv[j][2] + qv[3]*kv[j][3];
      }
    }
    unsigned Hi[2][4], Lo[2][4];
#pragma unroll
    for (int r = 0; r < 2; ++r) {
#pragma unroll
      for (int j = 0; j < 4; ++j) s[r][j] = s[r][j] / 8.0f;
      if (l == 63) s[r][3] = -1e30f;              // m = 255 invalid
      float mx = fmaxf(fmaxf(s[r][0], s[r][1]), fmaxf(s[r][2], s[r][3]));
      mx = wred_max_f32(mx);
      float ws = 0.f;
#pragma unroll
      for (int j = 0; j < 4; ++j) { s[r][j] = expf(s[r][j] - mx); ws += s[r][j]; }
      ws = wred_sum_f32(ws);
      unsigned long long key[4];
#pragma unroll
      for (int j = 0; j < 4; ++j) {
        s[r][j] = s[r][j] / ws;
        pl[w][r][64 * j + l] = s[r][j];
        key[j] = ((unsigned long long)__float_as_uint(s[r][j]) << 32)
               | (unsigned)(~(unsigned)(64 * j + l));
      }
      CE(key,0,1) CE(key,2,3) CE(key,0,2) CE(key,1,3) CE(key,1,2)
#pragma unroll
      for (int j = 0; j < 4; ++j) {
        Hi[r][j] = (unsigned)(key[j] >> 32); Lo[r][j] = (unsigned)key[j];
      }
    }
    float acc[2] = {0.f, 0.f};
#pragma unroll 4
    for (int m4 = 0; m4 < 256; m4 += 4) {
      f4 pv[2];
#pragma unroll
      for (int r = 0; r < 2; ++r) pv[r] = *(const f4*)&pl[w][r][m4];
      float v0 = Vl[(m4 + 0) * 64 + l];
      float v1 = Vl[(m4 + 1) * 64 + l];
      float v2v = Vl[(m4 + 2) * 64 + l];
      float v3 = Vl[(m4 + 3) * 64 + l];
#pragma unroll
      for (int r = 0; r < 2; ++r)
        acc[r] += pv[r][0]*v0 + pv[r][1]*v1 + pv[r][2]*v2v + pv[r][3]*v3;
    }
#pragma unroll
    for (int r = 0; r < 2; ++r) {
      int n = rbase + r;
      if (n < 255) {
        size_t off = ((size_t)g * 255 + n) * 64 + l;
        xt2[off] = x1g[off] + acc[r];
      }
    }
    int* io0 = idx2 + ((size_t)g * 255 + rbase + 0) * 20;
    int* io1 = idx2 + ((size_t)g * 255 + rbase + 1) * 20;
    for (int kk = 0; kk < 20; ++kk) {
      unsigned g0 = sel_round4(Hi[0], Lo[0], kk < 19);
      unsigned g1 = sel_round4(Hi[1], Lo[1], kk < 19);
      if (l == 0) {
        if (rbase + 0 < 255) io0[kk] = (int)(~g0);
        if (rbase + 1 < 255) io1[kk] = (int)(~g1);
      }
    }
  }
}

// ---------------- w2 transpose: w2T[c][o] --------------------------------
__global__ __launch_bounds__(256) void w2t_k(const float* __restrict__ w2,
                                             float* __restrict__ w2T) {
  int t = threadIdx.x;
  for (int i = t; i < 16384; i += 256) {
    int o = i >> 7, c = i & 127;
    w2T[c * 128 + o] = w2[o * 128 + c];
  }
}

// ---------------- conv2 (1x1, 128x128) + bn2 + lrelu + max over k --------
// 4 positions/block, 128 threads; LDS 21.5KB; weights from global w2T.
__global__ __launch_bounds__(128) void conv2_k(const float* __restrict__ xt2,
    const int* __restrict__ idx2, const float* __restrict__ w2T,
    const float* __restrict__ bg, const float* __restrict__ bb,
    float* __restrict__ x2g) {
  __shared__ __align__(16) float rowsT[4][64][20];  // [pos][c][k]
  __shared__ float ctr2[4][64];                     // [pos][c]
  int t = threadIdx.x, g = blockIdx.y;
  int n0 = blockIdx.x * 4;
  for (int i = t; i < 5120; i += 128) {
    int pos = i / 1280, rem = i % 1280, k = rem >> 6, c = rem & 63;
    int n = n0 + pos;
    float v = 0.f;
    if (n < 255) {
      int j = idx2[((size_t)g * 255 + n) * 20 + k];
      v = xt2[((size_t)g * 255 + j) * 64 + c];
    }
    rowsT[pos][c][k] = v;
  }
  for (int i = t; i < 256; i += 128) {
    int pos = i >> 6, c = i & 63;
    int n = n0 + pos;
    ctr2[pos][c] = (n < 255) ? xt2[((size_t)g * 255 + n) * 64 + c] : 0.f;
  }
  __syncthreads();
  int os = t & 31, np = t >> 5;   // np in 0..3
  float acc[4][20] = {};
  float t1[4] = {0.f, 0.f, 0.f, 0.f};
  for (int c = 0; c < 64; ++c) {
    f4 wq = *(const f4*)(w2T + c * 128 + os * 4);
    float cv = ctr2[np][c];
#pragma unroll
    for (int i = 0; i < 4; ++i) t1[i] += wq[i] * cv;
#pragma unroll
    for (int q = 0; q < 5; ++q) {
      f4 rv = *(const f4*)&rowsT[np][c][4 * q];
#pragma unroll
      for (int e = 0; e < 4; ++e)
#pragma unroll
        for (int i = 0; i < 4; ++i) acc[i][4 * q + e] += wq[i] * rv[e];
    }
  }
  float t2[4] = {0.f, 0.f, 0.f, 0.f};
  for (int c = 0; c < 64; ++c) {
    f4 wq = *(const f4*)(w2T + (64 + c) * 128 + os * 4);
    float cv = ctr2[np][c];
#pragma unroll
    for (int i = 0; i < 4; ++i) t2[i] += wq[i] * cv;
  }
  int n = n0 + np;
  f4 res;
#pragma unroll
  for (int i = 0; i < 4; ++i) {
    float vm = -1e30f;
#pragma unroll
    for (int j = 0; j < 20; ++j) vm = fmaxf(vm, acc[i][j]);
    vm += t2[i] - t1[i];
    int o = os * 4 + i;
    float sc = bg[o] / sqrtf(1.0f + BN_EPS);
    float z = sc * vm + bb[o];
    if (z < 0.f) z *= NEG;
    res[i] = z;
  }
  if (n < 255)
    *(f4*)&x2g[((size_t)g * 255 + n) * 128 + os * 4] = res;
}

// ---------------- conv5 (1x1, 1024x192) + bn5 + lrelu + max over n -------
// r14 body; red[] aliased onto colhT; XCD panel locality grid.
__global__ __launch_bounds__(256) void conv5_k(const float* __restrict__ x1g,
    const float* __restrict__ x2g, const float* __restrict__ w5,
    const float* __restrict__ bg, const float* __restrict__ bb,
    float* __restrict__ out, int ot0) {
  __shared__ __align__(16) float w5h[96 * 64];
  __shared__ __align__(16) float colhT[96][68];   // [c][n(64)+pad]
  float (*red)[64] = (float (*)[64])&colhT[0][0]; // overlay (colhT dead)
  int t = threadIdx.x;
  int px = blockIdx.x, ot = blockIdx.y + ot0;
  int fp = px & 7, b = px >> 3;
  size_t rowbase = ((size_t)b * 8 + fp) * 255;
  int os = t & 15, ns = t >> 4;
  float acc[4][4][4] = {};   // [grp][o4][n4]
  for (int ch = 0; ch < 2; ++ch) {
    __syncthreads();
    for (int i = t; i < 6144; i += 256) {
      int oL = i / 96, c = i % 96;
      w5h[c * 64 + (oL ^ (c & 28))] = w5[((size_t)(ot * 64 + oL)) * 192 + ch * 96 + c];
    }
#pragma unroll
    for (int grp = 0; grp < 4; ++grp) {
      __syncthreads();
      for (int i = t; i < 6144; i += 256) {
        int nl = i / 96, c = i % 96;
        int n = grp * 64 + nl;
        float v = 0.f;
        if (n < 255) {
          int cc = ch * 96 + c;
          v = (cc < 64) ? x1g[(rowbase + n) * 64 + cc]
                        : x2g[(rowbase + n) * 128 + (cc - 64)];
        }
        colhT[c][nl] = v;
      }
      __syncthreads();
      for (int c = 0; c < 96; ++c) {
        f4 wq = *(const f4*)&w5h[c * 64 + ((os * 4) ^ (c & 28))];
        f4 cv = *(const f4*)&colhT[c][ns * 4];
#pragma unroll
        for (int u = 0; u < 4; ++u)
#pragma unroll
          for (int vv = 0; vv < 4; ++vv) acc[grp][u][vv] += wq[u] * cv[vv];
      }
    }
  }
  float vm[4] = {-1e30f, -1e30f, -1e30f, -1e30f};
#pragma unroll
  for (int grp = 0; grp < 4; ++grp)
#pragma unroll
    for (int vv = 0; vv < 4; ++vv) {
      int n = grp * 64 + ns * 4 + vv;
      if (n < 255)
#pragma unroll
        for (int u = 0; u < 4; ++u) vm[u] = fmaxf(vm[u], acc[grp][u][vv]);
    }
  __syncthreads();                 // colhT fully dead before red overlay
#pragma unroll
  for (int u = 0; u < 4; ++u) red[ns][os * 4 + u] = vm[u];
  __syncthreads();
  if (t < 64) {
    float m = -1e30f;
#pragma unroll
    for (int q = 0; q < 16; ++q) m = fmaxf(m, red[q][t]);
    int o = ot * 64 + t;
    float sc = bg[o] / sqrtf(1.0f + BN_EPS);
    float z = sc * m + bb[o];
    if (z < 0.f) z *= NEG;
    out[((size_t)b * 8 + fp) * 1024 + o] = z;
  }
}

// ---------------- launcher ----------------------------------------------
extern "C" void kernel_launch(void* const* d_in, const int* in_sizes, int n_in,
                              void* d_out, int out_size, void* d_ws, size_t ws_size,
                              hipStream_t stream) {
  const float* x   = (const float*)d_in[0];
  const float* Wq1 = (const float*)d_in[1];
  const float* Wk1 = (const float*)d_in[2];
  const float* Wv1 = (const float*)d_in[3];
  const float* Wq2 = (const float*)d_in[4];
  const float* Wk2 = (const float*)d_in[5];
  const float* Wv2 = (const float*)d_in[6];
  const float* w1  = (const float*)d_in[7];
  const float* w2  = (const float*)d_in[8];
  const float* w5  = (const float*)d_in[9];
  const float* bg1 = (const float*)d_in[10];
  const float* bb1 = (const float*)d_in[11];
  const float* bg2 = (const float*)d_in[12];
  const float* bb2 = (const float*)d_in[13];
  const float* bg5 = (const float*)d_in[14];
  const float* bb5 = (const float*)d_in[15];
  float* out = (float*)d_out;
  float* ws  = (float*)d_ws;

  float* x1g  = ws;                       // 1044480
  float* xt1p = ws + 1048576;             // 524288
  int*   idx1 = (int*)(ws + 1572864);     // 2621440
  float* q2   = ws + 4194304;             // 1044480
  float* k2   = ws + 5238784;             // 1044480
  float* v2   = ws + 6283264;             // 1044480
  float* xt2  = ws + 7327744;             // 1044480
  int*   idx2 = (int*)(ws + 8372224);     // 326400
  float* x2g  = ws + 8698624;             // 2088960
  float* w2T  = ws + 10787584;            // 16384

  // independent prep first (no serialization bubble later)
  w2t_k<<<dim3(1), 256, 0, stream>>>(w2, w2T);
  // single-launch attn1 (diagnostic 4-way split removed)
  attn1_k<<<dim3(32, 256), 256, 0, stream>>>(x, Wq1, Wk1, Wv1, xt1p, idx1, 0);
  conv1_k<<<dim3(16, 8, 8), 256, 0, stream>>>(xt1p, idx1, w1, bg1, bb1, x1g);
  qkv2_k<<<dim3(8, 64), 256, 0, stream>>>(x1g, Wq2, Wk2, Wv2, q2, k2, v2);
  attn2_k<<<dim3(64, 4), 512, 0, stream>>>(q2, k2, v2, x1g, xt2, idx2);
  conv2_k<<<dim3(64, 64), 128, 0, stream>>>(xt2, idx2, w2T, bg2, bb2, x2g);
  // single-launch conv5 (diagnostic 2-way split removed)
  conv5_k<<<dim3(64, 16), 256, 0, stream>>>(x1g, x2g, w5, bg5, bb5, out, 0);
}